// Round 5
// baseline (262.573 us; speedup 1.0000x reference)
//
#include <hip/hip_runtime.h>

typedef unsigned short u16;
typedef unsigned int u32;
typedef unsigned long long u64;

typedef __bf16 bf16x8 __attribute__((ext_vector_type(8)));
typedef float f32x4 __attribute__((ext_vector_type(4)));
typedef u16 u16x4 __attribute__((ext_vector_type(4)));

__device__ __forceinline__ u16 f2bf(float f) {
  u32 u = __builtin_bit_cast(u32, f);
  u += 0x7fffu + ((u >> 16) & 1u);
  return (u16)(u >> 16);
}

__device__ __forceinline__ u32 packbf2(float a, float b) {
  __bf16 x = (__bf16)a, y = (__bf16)b;
  return (u32)__builtin_bit_cast(u16, x) | ((u32)__builtin_bit_cast(u16, y) << 16);
}

__device__ __forceinline__ float fexp2(float x) {
#if __has_builtin(__builtin_amdgcn_exp2f)
  return __builtin_amdgcn_exp2f(x);
#else
  return exp2f(x);
#endif
}

__device__ __forceinline__ void gload_lds16(const void* g, void* lds) {
  __builtin_amdgcn_global_load_lds(
      (const __attribute__((address_space(1))) void*)g,
      (__attribute__((address_space(3))) void*)lds, 16, 0, 0);
}

// 0.125 (1/sqrt(64)) * log2(e) — folded into Q projection so softmax runs in exp2 domain
#define QSCALE 0.18033688011112043f

// ---------------- cast x: fp32 -> bf16 ----------------
__global__ __launch_bounds__(256) void cast_f32_bf16(
    const float* __restrict__ in, u16* __restrict__ out, int n4) {
  int i = (blockIdx.x * 256 + threadIdx.x) * 4;
  float4 v = *reinterpret_cast<const float4*>(in + i);
  u16x4 o;
  o[0] = f2bf(v.x); o[1] = f2bf(v.y); o[2] = f2bf(v.z); o[3] = f2bf(v.w);
  *reinterpret_cast<u16x4*>(out + i) = o;
}

// ---------------- transpose + cast: w[K][N] fp32 -> wt[N][K] bf16 ----------------
__global__ __launch_bounds__(256) void transpose_cast(
    const float* __restrict__ w, u16* __restrict__ wt, int K, int N) {
  __shared__ float tile[32][33];
  int bx = blockIdx.x * 32;  // n
  int by = blockIdx.y * 32;  // k
  int tx = threadIdx.x & 31, ty = threadIdx.x >> 5;
#pragma unroll
  for (int i = 0; i < 32; i += 8)
    tile[ty + i][tx] = w[(size_t)(by + ty + i) * N + bx + tx];
  __syncthreads();
#pragma unroll
  for (int i = 0; i < 32; i += 8)
    wt[(size_t)(bx + ty + i) * K + by + tx] = f2bf(tile[tx][ty + i]);
}

// ---------------- transpose u16: V[4096][512] -> VT[B*512][2048] ----------------
__global__ __launch_bounds__(256) void transpose_u16(
    const u16* __restrict__ in, u16* __restrict__ out) {
  __shared__ u16 tile[32][33];
  int bx = blockIdx.x * 32;  // t dim
  int by = blockIdx.y * 32;  // col dim
  int bz = blockIdx.z;       // batch
  int tx = threadIdx.x & 31, ty = threadIdx.x >> 5;
#pragma unroll
  for (int i = 0; i < 32; i += 8)
    tile[ty + i][tx] = in[((size_t)bz * 2048 + bx + ty + i) * 512 + by + tx];
  __syncthreads();
#pragma unroll
  for (int i = 0; i < 32; i += 8)
    out[((size_t)bz * 512 + by + ty + i) * 2048 + bx + tx] = tile[tx][ty + i];
}

// ---------------- GEMM 256x256, BK=64, 8 waves, 8-phase-style deep pipeline ----
// C[M][N] = A[M][K](bf16) * BT[N][K](bf16), K == 2048.
// MODE 1: f32 out (ld=N). MODE 3: fused QKV split (cols [0,2048)->Cb scaled
// by QSCALE ld2048; [2048,2560)->Cb2 ld512; [2560,3072)->Cb3 ld512).
// Schedule per K-tile (4 phases, one 32-row A-quadrant each):
//   p0: ds_read A-quad + all B-frags | stage A0(t+1) | bar | MFMA16 | bar
//   p1: ds_read A-quad               | stage A1(t+1) | bar | MFMA16 | bar
//   p2: ds_read A-quad               | stage B0(t+2) | bar | MFMA16 | bar
//   p3: ds_read A-quad               | stage B1(t+2) | bar | MFMA16 | vmcnt(4) | bar
// Liveness: A(t) dies at p3 (overwritten by A(t+2) staged at (t+1,p0/p1));
// B(t) dies at p0 (read once into regs; overwritten by B(t+2) at (t,p2/p3)).
// vmcnt(4) leaves exactly the 2 youngest halves (B of t+2) in flight.
template <int MODE>
__global__ __launch_bounds__(512, 2) void gemm256(
    const u16* __restrict__ A, const u16* __restrict__ BT,
    float* __restrict__ Cf, u16* __restrict__ Cb, u16* __restrict__ Cb2,
    u16* __restrict__ Cb3, int M, int N, int K) {
  constexpr int NT = 32;  // K/64 == 2048/64
  __shared__ __align__(16) u16 Ab[2][256 * 64];
  __shared__ __align__(16) u16 Bb[2][256 * 64];
  const int t = threadIdx.x;
  const int lane = t & 63;
  const int w = t >> 6;
  const int wm = w >> 2, wn = w & 3;  // 2M x 4N wave grid; per-wave out 128x64
  const int l15 = lane & 15, l4 = lane >> 4;

  // XCD-aware bijective swizzle (nwg % 8 == 0 at both call sites)
  const int nwg = gridDim.x * gridDim.y;
  const int bid = blockIdx.y * gridDim.x + blockIdx.x;
  const int wg = (bid & 7) * (nwg >> 3) + (bid >> 3);
  const int brow = (wg / gridDim.x) * 256;
  const int bcol = (wg % gridDim.x) * 256;

  const int sg = t & 7;    // stage granule
  const int sr0 = t >> 3;  // stage row base 0..63

  auto stageA = [&](int q, int h, int kt) {
#pragma unroll
    for (int l = 0; l < 2; ++l) {
      int row = l * 64 + sr0;  // 0..127 within half
      int gsrc = (sg ^ (row & 7)) * 8;
      gload_lds16(&A[(size_t)(brow + h * 128 + row) * K + kt * 64 + gsrc],
                  &Ab[q][(h * 128 + row) * 64 + sg * 8]);
    }
  };
  auto stageB = [&](int q, int h, int kt) {
#pragma unroll
    for (int l = 0; l < 2; ++l) {
      int row = l * 64 + sr0;
      int gsrc = (sg ^ (row & 7)) * 8;
      gload_lds16(&BT[(size_t)(bcol + h * 128 + row) * K + kt * 64 + gsrc],
                  &Bb[q][(h * 128 + row) * 64 + sg * 8]);
    }
  };

  f32x4 acc[8][4];
#pragma unroll
  for (int mi = 0; mi < 8; mi++)
#pragma unroll
    for (int n = 0; n < 4; n++)
#pragma unroll
      for (int r = 0; r < 4; r++) acc[mi][n][r] = 0.f;

  // prologue: tile0 fully + B of tile1; wait tile0 landed (leave B(1) in flight)
  stageA(0, 0, 0); stageA(0, 1, 0);
  stageB(0, 0, 0); stageB(0, 1, 0);
  stageB(1, 0, 1); stageB(1, 1, 1);
  asm volatile("s_waitcnt vmcnt(4)" ::: "memory");
  __builtin_amdgcn_sched_barrier(0);
  __builtin_amdgcn_s_barrier();

  for (int kt = 0; kt < NT; ++kt) {
    const int q = kt & 1;
    const u16* Ah = &Ab[q][wm * 128 * 64];
    const u16* Bh = &Bb[q][wn * 64 * 64];
    bf16x8 bfr[4][2];
#pragma unroll
    for (int p = 0; p < 4; ++p) {
      // ---- ds-reads for this phase ----
      bf16x8 afr[2][2];
#pragma unroll
      for (int m2 = 0; m2 < 2; ++m2) {
        int row = p * 32 + m2 * 16 + l15;
#pragma unroll
        for (int ks = 0; ks < 2; ++ks)
          afr[m2][ks] = *reinterpret_cast<const bf16x8*>(
              &Ah[row * 64 + (((ks * 4 + l4) ^ (row & 7)) * 8)]);
      }
      if (p == 0) {
#pragma unroll
        for (int n = 0; n < 4; ++n) {
          int row = n * 16 + l15;
#pragma unroll
          for (int ks = 0; ks < 2; ++ks)
            bfr[n][ks] = *reinterpret_cast<const bf16x8*>(
                &Bh[row * 64 + ((((ks * 4 + l4)) ^ ((wn * 64 + row) & 7)) * 8)]);
        }
      }
      // ---- stage schedule ----
      if (p == 0 && kt + 1 < NT) stageA(q ^ 1, 0, kt + 1);
      if (p == 1 && kt + 1 < NT) stageA(q ^ 1, 1, kt + 1);
      if (p == 2 && kt + 2 < NT) stageB(q, 0, kt + 2);
      if (p == 3 && kt + 2 < NT) stageB(q, 1, kt + 2);

      __builtin_amdgcn_s_barrier();
      __builtin_amdgcn_s_setprio(1);
#pragma unroll
      for (int ks = 0; ks < 2; ++ks)
#pragma unroll
        for (int m2 = 0; m2 < 2; ++m2)
#pragma unroll
          for (int n = 0; n < 4; ++n)
            acc[p * 2 + m2][n] = __builtin_amdgcn_mfma_f32_16x16x32_bf16(
                afr[m2][ks], bfr[n][ks], acc[p * 2 + m2][n], 0, 0, 0);
      __builtin_amdgcn_s_setprio(0);
      if (p == 3) {
        if (kt + 2 < NT) {
          asm volatile("s_waitcnt vmcnt(4)" ::: "memory");
        } else {
          asm volatile("s_waitcnt vmcnt(0)" ::: "memory");
        }
        __builtin_amdgcn_sched_barrier(0);
      }
      __builtin_amdgcn_s_barrier();
    }
  }

  // ---- epilogue ----
#pragma unroll
  for (int mi = 0; mi < 8; ++mi) {
    int grow0 = brow + wm * 128 + mi * 16 + l4 * 4;
#pragma unroll
    for (int n = 0; n < 4; ++n) {
      int gcol = bcol + wn * 64 + n * 16 + l15;
#pragma unroll
      for (int r = 0; r < 4; ++r) {
        float v = acc[mi][n][r];
        if (MODE == 1) {
          Cf[(size_t)(grow0 + r) * N + gcol] = v;
        } else {
          if (bcol < 2048)
            Cb[(size_t)(grow0 + r) * 2048 + gcol] = f2bf(v * QSCALE);
          else if (bcol < 2560)
            Cb2[(size_t)(grow0 + r) * 512 + (gcol - 2048)] = f2bf(v);
          else
            Cb3[(size_t)(grow0 + r) * 512 + (gcol - 2560)] = f2bf(v);
        }
      }
    }
  }
}

// ---------------- flash attention (causal, GQA, swapped QK^T, paired q-tiles) --
// grid: (8, 32, 2). Block jj processes q-tile (15-jj) then q-tile jj (128 rows)
// -> every block does exactly 34 kv-tile-steps (perfect balance).
__global__ __launch_bounds__(256, 2) void attn_kernel(
    const u16* __restrict__ Qb, const u16* __restrict__ Kb,
    const u16* __restrict__ VT, u16* __restrict__ Ob) {
  const int jj = blockIdx.x;  // 0..7
  const int h = blockIdx.y, b = blockIdx.z;
  const int kvh = h >> 2;
  const int t = threadIdx.x;
  const int lane = t & 63;
  const int w = t >> 6;
  const int q15 = lane & 15, g = lane >> 4;

  __shared__ __align__(16) u16 Ks[2][64 * 64];
  __shared__ __align__(16) u16 Vs[2][64 * 64];  // V^T tile: [d][kv]
  __shared__ __align__(16) u32 Pu[4][16 * 32];  // per-wave P / epilogue buffer

  const size_t Krow0 = (size_t)b * 2048;
  const size_t Vrow0 = ((size_t)b * 8 + kvh) * 64;

  auto stage = [&](int buf, int kvbase) {
#pragma unroll
    for (int c = 0; c < 2; ++c) {
      int chunk = c * 256 + t;
      int row = chunk >> 3, gg = chunk & 7;
      int gcs = (gg ^ (row & 7)) * 8;
      gload_lds16(&Kb[(Krow0 + kvbase + row) * 512 + kvh * 64 + gcs],
                  &Ks[buf][chunk * 8]);
      gload_lds16(&VT[(Vrow0 + row) * 2048 + kvbase + gcs],
                  &Vs[buf][chunk * 8]);
    }
  };

  const int swzB = (q15 & 7) << 3;  // u16-unit frag-read swizzle (matches stage)
  const int swzP = (q15 & 7) << 2;  // u32-unit swizzle for Pu
  u32* const pw = &Pu[w][0];
  const int nA = 2 * (15 - jj) + 2;  // phase-A kv-steps
  const int nsteps = 34;

  stage(0, 0);
  __syncthreads();
  int cur = 0;
  int ss = 0;

#pragma unroll
  for (int ph = 0; ph < 2; ++ph) {
    const int qt = ph ? jj : 15 - jj;
    const int nkv = 2 * qt + 2;
    const int wq0 = qt * 128 + w * 32;
    const int mylast = (wq0 + 31) >> 6;

    // Q fragments: qf[sub][ks] — B-operand layout (row=q15, k-chunk=g*8)
    bf16x8 qf[2][2];
    {
      const u16* q0 = &Qb[((size_t)b * 2048 + wq0 + q15) * 2048 + h * 64 + g * 8];
      qf[0][0] = *reinterpret_cast<const bf16x8*>(q0);
      qf[0][1] = *reinterpret_cast<const bf16x8*>(q0 + 32);
      qf[1][0] = *reinterpret_cast<const bf16x8*>(q0 + 16 * 2048);
      qf[1][1] = *reinterpret_cast<const bf16x8*>(q0 + 16 * 2048 + 32);
    }

    f32x4 oo[2][4];  // O^T accum: oo[sub][c2], d = c2*16+g*4+r, col q=q15
#pragma unroll
    for (int s2 = 0; s2 < 2; s2++)
#pragma unroll
      for (int c = 0; c < 4; c++)
#pragma unroll
        for (int r = 0; r < 4; r++) oo[s2][c][r] = 0.f;
    float mr[2] = {-1e30f, -1e30f}, lr[2] = {0.f, 0.f};

    for (int kv = 0; kv < nkv; ++kv, ++ss) {
      const int kvbase = kv << 6;
      if (ss + 1 < nsteps) {
        int nb = (ss + 1 < nA) ? (ss + 1) : (ss + 1 - nA);
        stage(cur ^ 1, nb << 6);
      }

      if (kv <= mylast) {
        // ---- S^T = K Q^T : D[kv][q] ----
        f32x4 s[2][4];
#pragma unroll
        for (int s2 = 0; s2 < 2; s2++)
#pragma unroll
          for (int c = 0; c < 4; c++)
#pragma unroll
            for (int r = 0; r < 4; r++) s[s2][c][r] = 0.f;
        __builtin_amdgcn_s_setprio(1);
#pragma unroll
        for (int ks = 0; ks < 2; ++ks) {
          const int kcol = (ks * 32 + g * 8) ^ swzB;
#pragma unroll
          for (int c = 0; c < 4; c++) {
            bf16x8 kb = *reinterpret_cast<const bf16x8*>(
                &Ks[cur][(c * 16 + q15) * 64 + kcol]);
            s[0][c] = __builtin_amdgcn_mfma_f32_16x16x32_bf16(kb, qf[0][ks], s[0][c], 0, 0, 0);
            s[1][c] = __builtin_amdgcn_mfma_f32_16x16x32_bf16(kb, qf[1][ks], s[1][c], 0, 0, 0);
          }
        }
        __builtin_amdgcn_s_setprio(0);

        bf16x8 pb[2][2];
#pragma unroll
        for (int sub = 0; sub < 2; ++sub) {
          const int qg = wq0 + sub * 16 + q15;
          // causal mask (diagonal tiles only; wave-uniform branch)
          if (kvbase + 63 > wq0 + sub * 16) {
#pragma unroll
            for (int c = 0; c < 4; c++)
#pragma unroll
              for (int r = 0; r < 4; r++)
                if (kvbase + c * 16 + g * 4 + r > qg) s[sub][c][r] = -1e30f;
          }
          // in-lane max over 16, then cross-g reduce (2 shfl)
          float mx0 = fmaxf(fmaxf(s[sub][0][0], s[sub][0][1]), fmaxf(s[sub][0][2], s[sub][0][3]));
          float mx1 = fmaxf(fmaxf(s[sub][1][0], s[sub][1][1]), fmaxf(s[sub][1][2], s[sub][1][3]));
          float mx2 = fmaxf(fmaxf(s[sub][2][0], s[sub][2][1]), fmaxf(s[sub][2][2], s[sub][2][3]));
          float mx3 = fmaxf(fmaxf(s[sub][3][0], s[sub][3][1]), fmaxf(s[sub][3][2], s[sub][3][3]));
          float mx = fmaxf(fmaxf(mx0, mx1), fmaxf(mx2, mx3));
          mx = fmaxf(mx, __shfl_xor(mx, 16));
          mx = fmaxf(mx, __shfl_xor(mx, 32));
          // defer-max (T13): only rescale when tile max meaningfully exceeds mr
          if (!__all(mx <= mr[sub] + 8.f)) {
            float mnew = fmaxf(mr[sub], mx);
            float alpha = fexp2(mr[sub] - mnew);
            lr[sub] *= alpha;
#pragma unroll
            for (int c = 0; c < 4; c++)
#pragma unroll
              for (int r = 0; r < 4; r++) oo[sub][c][r] *= alpha;
            mr[sub] = mnew;
          }
          float p[4][4];
          float rs = 0.f;
#pragma unroll
          for (int c = 0; c < 4; c++) {
            float t0 = fexp2(s[sub][c][0] - mr[sub]);
            float t1 = fexp2(s[sub][c][1] - mr[sub]);
            float t2 = fexp2(s[sub][c][2] - mr[sub]);
            float t3 = fexp2(s[sub][c][3] - mr[sub]);
            p[c][0] = t0; p[c][1] = t1; p[c][2] = t2; p[c][3] = t3;
            rs += (t0 + t1) + (t2 + t3);
          }
          rs += __shfl_xor(rs, 16);
          rs += __shfl_xor(rs, 32);
          lr[sub] += rs;
          // pack P -> per-wave LDS (b64 writes, K-style swizzle)
#pragma unroll
          for (int c = 0; c < 4; c++) {
            u64 wv = (u64)packbf2(p[c][0], p[c][1]) |
                     ((u64)packbf2(p[c][2], p[c][3]) << 32);
            *reinterpret_cast<u64*>(&pw[q15 * 32 + ((c * 8 + g * 2) ^ swzP)]) = wv;
          }
          // read back as B-fragment (row=q15, kv-chunk=g*8)
#pragma unroll
          for (int ks = 0; ks < 2; ++ks)
            pb[sub][ks] = *reinterpret_cast<const bf16x8*>(
                &pw[q15 * 32 + ((ks * 16 + g * 4) ^ swzP)]);
        }

        // ---- O^T += V^T P : D[d][q] ----
        __builtin_amdgcn_s_setprio(1);
#pragma unroll
        for (int ks = 0; ks < 2; ++ks) {
          const int vcol = (ks * 32 + g * 8) ^ swzB;
#pragma unroll
          for (int c2 = 0; c2 < 4; c2++) {
            bf16x8 vb = *reinterpret_cast<const bf16x8*>(
                &Vs[cur][(c2 * 16 + q15) * 64 + vcol]);
            oo[0][c2] = __builtin_amdgcn_mfma_f32_16x16x32_bf16(vb, pb[0][ks], oo[0][c2], 0, 0, 0);
            oo[1][c2] = __builtin_amdgcn_mfma_f32_16x16x32_bf16(vb, pb[1][ks], oo[1][c2], 0, 0, 0);
          }
        }
        __builtin_amdgcn_s_setprio(0);
      }

      __syncthreads();
      cur ^= 1;
    }

    // ---- epilogue: normalize, transpose via per-wave LDS, coalesced store ----
    const int qq = lane >> 2, cl = lane & 3;
    const int swq = (qq & 7) << 2;
#pragma unroll
    for (int sub = 0; sub < 2; ++sub) {
      float rcp = 1.0f / lr[sub];
#pragma unroll
      for (int c2 = 0; c2 < 4; c2++) {
        u64 wv = (u64)packbf2(oo[sub][c2][0] * rcp, oo[sub][c2][1] * rcp) |
                 ((u64)packbf2(oo[sub][c2][2] * rcp, oo[sub][c2][3] * rcp) << 32);
        *reinterpret_cast<u64*>(&pw[q15 * 32 + ((c2 * 8 + g * 2) ^ swzP)]) = wv;
      }
      uint4 d0 = *reinterpret_cast<const uint4*>(&pw[qq * 32 + ((cl * 4) ^ swq)]);
      uint4 d1 = *reinterpret_cast<const uint4*>(&pw[qq * 32 + ((cl * 4 + 16) ^ swq)]);
      u32* og = (u32*)Ob + ((size_t)b * 2048 + wq0 + sub * 16 + qq) * 1024 + h * 32;
      *reinterpret_cast<uint4*>(&og[cl * 4]) = d0;
      *reinterpret_cast<uint4*>(&og[cl * 4 + 16]) = d1;
    }
  }
}

// ---------------- launcher ----------------
extern "C" void kernel_launch(void* const* d_in, const int* in_sizes, int n_in,
                              void* d_out, int out_size, void* d_ws, size_t ws_size,
                              hipStream_t stream) {
  const float* x = (const float*)d_in[0];
  const float* wq = (const float*)d_in[1];
  const float* wk = (const float*)d_in[2];
  const float* wv = (const float*)d_in[3];
  const float* wo = (const float*)d_in[4];
  float* out = (float*)d_out;

  char* p = (char*)d_ws;
  u16* xb = (u16*)p;   p += (size_t)4096 * 2048 * 2;
  u16* wqT = (u16*)p;  p += (size_t)2048 * 2048 * 2;  // wqT|wkT|wvT contiguous:
  u16* wkT = (u16*)p;  p += (size_t)512 * 2048 * 2;   //   fused QKV GEMM reads
  u16* wvT = (u16*)p;  p += (size_t)512 * 2048 * 2;   //   them as one 3072x2048 BT
  u16* woT = (u16*)p;  p += (size_t)2048 * 2048 * 2;
  u16* Qb = (u16*)p;   p += (size_t)4096 * 2048 * 2;
  u16* Kb = (u16*)p;   p += (size_t)4096 * 512 * 2;
  u16* Vb = (u16*)p;   p += (size_t)4096 * 512 * 2;
  u16* VTb = (u16*)p;  p += (size_t)2 * 512 * 2048 * 2;
  u16* attn = xb;  // reuse: x_bf16 dead after projections

  cast_f32_bf16<<<8192, 256, 0, stream>>>(x, xb, 4096 * 2048);
  transpose_cast<<<dim3(2048 / 32, 2048 / 32), 256, 0, stream>>>(wq, wqT, 2048, 2048);
  transpose_cast<<<dim3(512 / 32, 2048 / 32), 256, 0, stream>>>(wk, wkT, 2048, 512);
  transpose_cast<<<dim3(512 / 32, 2048 / 32), 256, 0, stream>>>(wv, wvT, 2048, 512);
  transpose_cast<<<dim3(2048 / 32, 2048 / 32), 256, 0, stream>>>(wo, woT, 2048, 2048);

  // fused Q|K|V projection (Q pre-scaled by QSCALE inside epilogue)
  gemm256<3><<<dim3(3072 / 256, 4096 / 256), 512, 0, stream>>>(
      xb, wqT, nullptr, Qb, Kb, Vb, 4096, 3072, 2048);

  transpose_u16<<<dim3(2048 / 32, 512 / 32, 2), 256, 0, stream>>>(Vb, VTb);

  attn_kernel<<<dim3(8, 32, 2), 256, 0, stream>>>(Qb, Kb, VTb, attn);

  gemm256<1><<<dim3(2048 / 256, 4096 / 256), 512, 0, stream>>>(
      attn, woT, out, nullptr, nullptr, nullptr, 4096, 2048, 2048);
}

// Round 6
// 238.666 us; speedup vs baseline: 1.1002x; 1.1002x over previous
//
#include <hip/hip_runtime.h>

typedef unsigned short u16;
typedef unsigned int u32;
typedef unsigned long long u64;

typedef __bf16 bf16x8 __attribute__((ext_vector_type(8)));
typedef float f32x4 __attribute__((ext_vector_type(4)));
typedef u16 u16x4 __attribute__((ext_vector_type(4)));

__device__ __forceinline__ u16 f2bf(float f) {
  u32 u = __builtin_bit_cast(u32, f);
  u += 0x7fffu + ((u >> 16) & 1u);
  return (u16)(u >> 16);
}

__device__ __forceinline__ u32 packbf2(float a, float b) {
  __bf16 x = (__bf16)a, y = (__bf16)b;
  return (u32)__builtin_bit_cast(u16, x) | ((u32)__builtin_bit_cast(u16, y) << 16);
}

__device__ __forceinline__ float fexp2(float x) {
#if __has_builtin(__builtin_amdgcn_exp2f)
  return __builtin_amdgcn_exp2f(x);
#else
  return exp2f(x);
#endif
}

__device__ __forceinline__ void gload_lds16(const void* g, void* lds) {
  __builtin_amdgcn_global_load_lds(
      (const __attribute__((address_space(1))) void*)g,
      (__attribute__((address_space(3))) void*)lds, 16, 0, 0);
}

// 0.125 (1/sqrt(64)) * log2(e) — folded into Q projection so softmax runs in exp2 domain
#define QSCALE 0.18033688011112043f

// ---------------- cast x: fp32 -> bf16 ----------------
__global__ __launch_bounds__(256) void cast_f32_bf16(
    const float* __restrict__ in, u16* __restrict__ out, int n4) {
  int i = (blockIdx.x * 256 + threadIdx.x) * 4;
  float4 v = *reinterpret_cast<const float4*>(in + i);
  u16x4 o;
  o[0] = f2bf(v.x); o[1] = f2bf(v.y); o[2] = f2bf(v.z); o[3] = f2bf(v.w);
  *reinterpret_cast<u16x4*>(out + i) = o;
}

// ---------------- transpose + cast: w[K][N] fp32 -> wt[N][K] bf16 ----------------
__global__ __launch_bounds__(256) void transpose_cast(
    const float* __restrict__ w, u16* __restrict__ wt, int K, int N) {
  __shared__ float tile[32][33];
  int bx = blockIdx.x * 32;  // n
  int by = blockIdx.y * 32;  // k
  int tx = threadIdx.x & 31, ty = threadIdx.x >> 5;
#pragma unroll
  for (int i = 0; i < 32; i += 8)
    tile[ty + i][tx] = w[(size_t)(by + ty + i) * N + bx + tx];
  __syncthreads();
#pragma unroll
  for (int i = 0; i < 32; i += 8)
    wt[(size_t)(bx + ty + i) * K + by + tx] = f2bf(tile[tx][ty + i]);
}

// ---------------- transpose u16: V[4096][512] -> VT[B*512][2048] ----------------
__global__ __launch_bounds__(256) void transpose_u16(
    const u16* __restrict__ in, u16* __restrict__ out) {
  __shared__ u16 tile[32][33];
  int bx = blockIdx.x * 32;  // t dim
  int by = blockIdx.y * 32;  // col dim
  int bz = blockIdx.z;       // batch
  int tx = threadIdx.x & 31, ty = threadIdx.x >> 5;
#pragma unroll
  for (int i = 0; i < 32; i += 8)
    tile[ty + i][tx] = in[((size_t)bz * 2048 + bx + ty + i) * 512 + by + tx];
  __syncthreads();
#pragma unroll
  for (int i = 0; i < 32; i += 8)
    out[((size_t)bz * 512 + by + ty + i) * 2048 + bx + tx] = tile[tx][ty + i];
}

// ---------------- GEMM: C[M][N] = A[M][K](bf16) * BT[N][K](bf16) ----------------
// 128x128 tile, BK=32, 4 waves (proven best grid-fill at these shapes; 256^2
// tiles leave 25-50% of CUs idle at M=4096,N<=3072 — R5 regression).
// MODE 1: f32 out (ld=N). MODE 3: fused QKV split — cols [0,2048) -> Cb (Q, ld2048,
// scaled by QSCALE), [2048,2560) -> Cb2 (K, ld512), [2560,3072) -> Cb3 (V, ld512).
// XCD-aware bijective block swizzle (requires nwg % 8 == 0).
template <int MODE>
__global__ __launch_bounds__(256) void gemm_bt(
    const u16* __restrict__ A, const u16* __restrict__ BT,
    float* __restrict__ Cf, u16* __restrict__ Cb, u16* __restrict__ Cb2,
    u16* __restrict__ Cb3, int M, int N, int K) {
  __shared__ __align__(16) u16 As[128 * 32];
  __shared__ __align__(16) u16 Bs[128 * 32];
  const int t = threadIdx.x;
  const int lane = t & 63;
  const int w = t >> 6;
  const int wr = w >> 1, wc = w & 1;
  const int l15 = lane & 15;
  const int l4 = lane >> 4;

  // XCD swizzle: each XCD gets a contiguous chunk of the row-major tile space
  const int nwg = gridDim.x * gridDim.y;
  const int bid = blockIdx.y * gridDim.x + blockIdx.x;
  const int wg = (bid & 7) * (nwg >> 3) + (bid >> 3);
  const int brow = (wg / gridDim.x) * 128;
  const int bcol = (wg % gridDim.x) * 128;

  f32x4 acc[4][4];
#pragma unroll
  for (int m = 0; m < 4; m++)
#pragma unroll
    for (int n = 0; n < 4; n++)
#pragma unroll
      for (int r = 0; r < 4; r++) acc[m][n][r] = 0.f;

  const size_t Arow0 = (size_t)brow * K;
  const size_t Brow0 = (size_t)bcol * K;

  for (int kk = 0; kk < K; kk += 32) {
#pragma unroll
    for (int c = 0; c < 2; ++c) {
      int chunk = c * 256 + t;
      int row = chunk >> 2;
      int col = (chunk & 3) * 8;
      gload_lds16(&A[Arow0 + (size_t)row * K + kk + col], &As[chunk * 8]);
      gload_lds16(&BT[Brow0 + (size_t)row * K + kk + col], &Bs[chunk * 8]);
    }
    __syncthreads();
    const int k0 = l4 * 8;
    bf16x8 a[4], b[4];
#pragma unroll
    for (int m = 0; m < 4; m++)
      a[m] = *reinterpret_cast<const bf16x8*>(&As[(wr * 64 + m * 16 + l15) * 32 + k0]);
#pragma unroll
    for (int n = 0; n < 4; n++)
      b[n] = *reinterpret_cast<const bf16x8*>(&Bs[(wc * 64 + n * 16 + l15) * 32 + k0]);
#pragma unroll
    for (int m = 0; m < 4; m++)
#pragma unroll
      for (int n = 0; n < 4; n++)
        acc[m][n] = __builtin_amdgcn_mfma_f32_16x16x32_bf16(a[m], b[n], acc[m][n], 0, 0, 0);
    __syncthreads();
  }

#pragma unroll
  for (int m = 0; m < 4; m++) {
    int grow0 = brow + wr * 64 + m * 16 + l4 * 4;
#pragma unroll
    for (int n = 0; n < 4; n++) {
      int gcol = bcol + wc * 64 + n * 16 + l15;
#pragma unroll
      for (int r = 0; r < 4; r++) {
        if (MODE == 1) {
          Cf[(size_t)(grow0 + r) * N + gcol] = acc[m][n][r];
        } else {  // MODE 3 — bcol is 128-aligned so whole block is in one region
          if (bcol < 2048)
            Cb[(size_t)(grow0 + r) * 2048 + gcol] = f2bf(acc[m][n][r] * QSCALE);
          else if (bcol < 2560)
            Cb2[(size_t)(grow0 + r) * 512 + (gcol - 2048)] = f2bf(acc[m][n][r]);
          else
            Cb3[(size_t)(grow0 + r) * 512 + (gcol - 2560)] = f2bf(acc[m][n][r]);
        }
      }
    }
  }
}

// ---------------- flash attention v5 (causal, GQA, swapped QK^T, paired q-tiles,
//                  triple-buffered K/V with counted vmcnt — T3/T4-minimum) --------
// grid: (8, 32, 2). Block jj processes q-tile (15-jj) then q-tile jj (128 rows)
// -> every block does exactly 34 kv-tile-steps (perfect balance).
// 4 waves; wave w owns rows [qt*128 + w*32, +32) (2 subtiles of 16).
// Swapped mfma(K,Q): lane (g=l>>4, q=l&15) holds S^T[kv = c*16+g*4+r][q].
// Pipeline: stage(ss+2) issued at top of step ss; step ends with
// s_waitcnt vmcnt(4) (own stage(ss+1) landed, stage(ss+2) in flight) + s_barrier.
// Never vmcnt(0) in the main loop (only in the 2-step tail).
__global__ __launch_bounds__(256, 2) void attn_kernel(
    const u16* __restrict__ Qb, const u16* __restrict__ Kb,
    const u16* __restrict__ VT, u16* __restrict__ Ob) {
  const int jj = blockIdx.x;  // 0..7
  const int h = blockIdx.y, b = blockIdx.z;
  const int kvh = h >> 2;
  const int t = threadIdx.x;
  const int lane = t & 63;
  const int w = t >> 6;
  const int q15 = lane & 15, g = lane >> 4;

  __shared__ __align__(16) u16 Ks[3][64 * 64];
  __shared__ __align__(16) u16 Vs[3][64 * 64];  // V^T tile: [d][kv]
  __shared__ __align__(16) u32 Pu[4][16 * 32];  // per-wave P / epilogue buffer

  const size_t Krow0 = (size_t)b * 2048;
  const size_t Vrow0 = ((size_t)b * 8 + kvh) * 64;

  // one stage = exactly 4 gload_lds16 per thread (vmcnt granularity)
  auto stage = [&](int buf, int kvbase) {
#pragma unroll
    for (int c = 0; c < 2; ++c) {
      int chunk = c * 256 + t;
      int row = chunk >> 3, gg = chunk & 7;
      int gcs = (gg ^ (row & 7)) * 8;
      gload_lds16(&Kb[(Krow0 + kvbase + row) * 512 + kvh * 64 + gcs],
                  &Ks[buf][chunk * 8]);
      gload_lds16(&VT[(Vrow0 + row) * 2048 + kvbase + gcs],
                  &Vs[buf][chunk * 8]);
    }
  };

  const int swzB = (q15 & 7) << 3;  // u16-unit frag-read swizzle (matches stage)
  const int swzP = (q15 & 7) << 2;  // u32-unit swizzle for Pu
  u32* const pw = &Pu[w][0];
  const int nA = 2 * (15 - jj) + 2;  // phase-A kv-steps
  const int nsteps = 34;
  // global step -> kv tile base
  auto kvb_of = [&](int ss) { return ((ss < nA) ? ss : ss - nA) << 6; };

  // prologue: stage steps 0 and 1; wait own stage(0) (leave stage(1) in flight)
  stage(0, kvb_of(0));
  stage(1, kvb_of(1));
  asm volatile("s_waitcnt vmcnt(4)" ::: "memory");
  __builtin_amdgcn_sched_barrier(0);
  __builtin_amdgcn_s_barrier();

  int cur = 0;
  int ss = 0;

#pragma unroll
  for (int ph = 0; ph < 2; ++ph) {
    const int qt = ph ? jj : 15 - jj;
    const int nkv = 2 * qt + 2;
    const int wq0 = qt * 128 + w * 32;
    const int mylast = (wq0 + 31) >> 6;

    // Q fragments: qf[sub][ks] — B-operand layout (row=q15, k-chunk=g*8)
    bf16x8 qf[2][2];
    {
      const u16* q0 = &Qb[((size_t)b * 2048 + wq0 + q15) * 2048 + h * 64 + g * 8];
      qf[0][0] = *reinterpret_cast<const bf16x8*>(q0);
      qf[0][1] = *reinterpret_cast<const bf16x8*>(q0 + 32);
      qf[1][0] = *reinterpret_cast<const bf16x8*>(q0 + 16 * 2048);
      qf[1][1] = *reinterpret_cast<const bf16x8*>(q0 + 16 * 2048 + 32);
    }

    f32x4 oo[2][4];  // O^T accum: oo[sub][c2], d = c2*16+g*4+r, col q=q15
#pragma unroll
    for (int s2 = 0; s2 < 2; s2++)
#pragma unroll
      for (int c = 0; c < 4; c++)
#pragma unroll
        for (int r = 0; r < 4; r++) oo[s2][c][r] = 0.f;
    float mr[2] = {-1e30f, -1e30f}, lr[2] = {0.f, 0.f};

    for (int kv = 0; kv < nkv; ++kv, ++ss) {
      const int kvbase = kv << 6;
      const bool staged = (ss + 2 < nsteps);
      if (staged) stage((cur + 2) % 3, kvb_of(ss + 2));

      if (kv <= mylast) {
        // ---- S^T = K Q^T : D[kv][q] ----
        f32x4 s[2][4];
#pragma unroll
        for (int s2 = 0; s2 < 2; s2++)
#pragma unroll
          for (int c = 0; c < 4; c++)
#pragma unroll
            for (int r = 0; r < 4; r++) s[s2][c][r] = 0.f;
        __builtin_amdgcn_s_setprio(1);
#pragma unroll
        for (int ks = 0; ks < 2; ++ks) {
          const int kcol = (ks * 32 + g * 8) ^ swzB;
#pragma unroll
          for (int c = 0; c < 4; c++) {
            bf16x8 kb = *reinterpret_cast<const bf16x8*>(
                &Ks[cur][(c * 16 + q15) * 64 + kcol]);
            s[0][c] = __builtin_amdgcn_mfma_f32_16x16x32_bf16(kb, qf[0][ks], s[0][c], 0, 0, 0);
            s[1][c] = __builtin_amdgcn_mfma_f32_16x16x32_bf16(kb, qf[1][ks], s[1][c], 0, 0, 0);
          }
        }
        __builtin_amdgcn_s_setprio(0);

        bf16x8 pb[2][2];
#pragma unroll
        for (int sub = 0; sub < 2; ++sub) {
          const int qg = wq0 + sub * 16 + q15;
          // causal mask (diagonal tiles only; wave-uniform branch)
          if (kvbase + 63 > wq0 + sub * 16) {
#pragma unroll
            for (int c = 0; c < 4; c++)
#pragma unroll
              for (int r = 0; r < 4; r++)
                if (kvbase + c * 16 + g * 4 + r > qg) s[sub][c][r] = -1e30f;
          }
          // in-lane max over 16, then cross-g reduce (2 shfl)
          float mx0 = fmaxf(fmaxf(s[sub][0][0], s[sub][0][1]), fmaxf(s[sub][0][2], s[sub][0][3]));
          float mx1 = fmaxf(fmaxf(s[sub][1][0], s[sub][1][1]), fmaxf(s[sub][1][2], s[sub][1][3]));
          float mx2 = fmaxf(fmaxf(s[sub][2][0], s[sub][2][1]), fmaxf(s[sub][2][2], s[sub][2][3]));
          float mx3 = fmaxf(fmaxf(s[sub][3][0], s[sub][3][1]), fmaxf(s[sub][3][2], s[sub][3][3]));
          float mx = fmaxf(fmaxf(mx0, mx1), fmaxf(mx2, mx3));
          mx = fmaxf(mx, __shfl_xor(mx, 16));
          mx = fmaxf(mx, __shfl_xor(mx, 32));
          // defer-max (T13): only rescale when tile max meaningfully exceeds mr
          if (!__all(mx <= mr[sub] + 8.f)) {
            float mnew = fmaxf(mr[sub], mx);
            float alpha = fexp2(mr[sub] - mnew);
            lr[sub] *= alpha;
#pragma unroll
            for (int c = 0; c < 4; c++)
#pragma unroll
              for (int r = 0; r < 4; r++) oo[sub][c][r] *= alpha;
            mr[sub] = mnew;
          }
          float p[4][4];
          float rs = 0.f;
#pragma unroll
          for (int c = 0; c < 4; c++) {
            float t0 = fexp2(s[sub][c][0] - mr[sub]);
            float t1 = fexp2(s[sub][c][1] - mr[sub]);
            float t2 = fexp2(s[sub][c][2] - mr[sub]);
            float t3 = fexp2(s[sub][c][3] - mr[sub]);
            p[c][0] = t0; p[c][1] = t1; p[c][2] = t2; p[c][3] = t3;
            rs += (t0 + t1) + (t2 + t3);
          }
          rs += __shfl_xor(rs, 16);
          rs += __shfl_xor(rs, 32);
          lr[sub] += rs;
          // pack P -> per-wave LDS (b64 writes, K-style swizzle)
#pragma unroll
          for (int c = 0; c < 4; c++) {
            u64 wv = (u64)packbf2(p[c][0], p[c][1]) |
                     ((u64)packbf2(p[c][2], p[c][3]) << 32);
            *reinterpret_cast<u64*>(&pw[q15 * 32 + ((c * 8 + g * 2) ^ swzP)]) = wv;
          }
          // read back as B-fragment (row=q15, kv-chunk=g*8)
#pragma unroll
          for (int ks = 0; ks < 2; ++ks)
            pb[sub][ks] = *reinterpret_cast<const bf16x8*>(
                &pw[q15 * 32 + ((ks * 16 + g * 4) ^ swzP)]);
        }

        // ---- O^T += V^T P : D[d][q] ----
        __builtin_amdgcn_s_setprio(1);
#pragma unroll
        for (int ks = 0; ks < 2; ++ks) {
          const int vcol = (ks * 32 + g * 8) ^ swzB;
#pragma unroll
          for (int c2 = 0; c2 < 4; c2++) {
            bf16x8 vb = *reinterpret_cast<const bf16x8*>(
                &Vs[cur][(c2 * 16 + q15) * 64 + vcol]);
            oo[0][c2] = __builtin_amdgcn_mfma_f32_16x16x32_bf16(vb, pb[0][ks], oo[0][c2], 0, 0, 0);
            oo[1][c2] = __builtin_amdgcn_mfma_f32_16x16x32_bf16(vb, pb[1][ks], oo[1][c2], 0, 0, 0);
          }
        }
        __builtin_amdgcn_s_setprio(0);
      }

      // end of step: own stage(ss+1) must have landed before any wave reads it
      // next step; stage(ss+2) (4 youngest loads) stays in flight.
      if (staged) {
        asm volatile("s_waitcnt vmcnt(4)" ::: "memory");
      } else {
        asm volatile("s_waitcnt vmcnt(0)" ::: "memory");
      }
      __builtin_amdgcn_sched_barrier(0);
      __builtin_amdgcn_s_barrier();
      cur = (cur == 2) ? 0 : cur + 1;
    }

    // ---- epilogue: normalize, transpose via per-wave LDS, coalesced store ----
    const int qq = lane >> 2, cl = lane & 3;
    const int swq = (qq & 7) << 2;
#pragma unroll
    for (int sub = 0; sub < 2; ++sub) {
      float rcp = 1.0f / lr[sub];
#pragma unroll
      for (int c2 = 0; c2 < 4; c2++) {
        u64 wv = (u64)packbf2(oo[sub][c2][0] * rcp, oo[sub][c2][1] * rcp) |
                 ((u64)packbf2(oo[sub][c2][2] * rcp, oo[sub][c2][3] * rcp) << 32);
        *reinterpret_cast<u64*>(&pw[q15 * 32 + ((c2 * 8 + g * 2) ^ swzP)]) = wv;
      }
      uint4 d0 = *reinterpret_cast<const uint4*>(&pw[qq * 32 + ((cl * 4) ^ swq)]);
      uint4 d1 = *reinterpret_cast<const uint4*>(&pw[qq * 32 + ((cl * 4 + 16) ^ swq)]);
      u32* og = (u32*)Ob + ((size_t)b * 2048 + wq0 + sub * 16 + qq) * 1024 + h * 32;
      *reinterpret_cast<uint4*>(&og[cl * 4]) = d0;
      *reinterpret_cast<uint4*>(&og[cl * 4 + 16]) = d1;
    }
  }
}

// ---------------- launcher ----------------
extern "C" void kernel_launch(void* const* d_in, const int* in_sizes, int n_in,
                              void* d_out, int out_size, void* d_ws, size_t ws_size,
                              hipStream_t stream) {
  const float* x = (const float*)d_in[0];
  const float* wq = (const float*)d_in[1];
  const float* wk = (const float*)d_in[2];
  const float* wv = (const float*)d_in[3];
  const float* wo = (const float*)d_in[4];
  float* out = (float*)d_out;

  char* p = (char*)d_ws;
  u16* xb = (u16*)p;   p += (size_t)4096 * 2048 * 2;
  u16* wqT = (u16*)p;  p += (size_t)2048 * 2048 * 2;  // wqT|wkT|wvT contiguous:
  u16* wkT = (u16*)p;  p += (size_t)512 * 2048 * 2;   //   fused QKV GEMM reads
  u16* wvT = (u16*)p;  p += (size_t)512 * 2048 * 2;   //   them as one 3072x2048 BT
  u16* woT = (u16*)p;  p += (size_t)2048 * 2048 * 2;
  u16* Qb = (u16*)p;   p += (size_t)4096 * 2048 * 2;
  u16* Kb = (u16*)p;   p += (size_t)4096 * 512 * 2;
  u16* Vb = (u16*)p;   p += (size_t)4096 * 512 * 2;
  u16* VTb = (u16*)p;  p += (size_t)2 * 512 * 2048 * 2;
  u16* attn = xb;  // reuse: x_bf16 dead after projections

  cast_f32_bf16<<<8192, 256, 0, stream>>>(x, xb, 4096 * 2048);
  transpose_cast<<<dim3(2048 / 32, 2048 / 32), 256, 0, stream>>>(wq, wqT, 2048, 2048);
  transpose_cast<<<dim3(512 / 32, 2048 / 32), 256, 0, stream>>>(wk, wkT, 2048, 512);
  transpose_cast<<<dim3(512 / 32, 2048 / 32), 256, 0, stream>>>(wv, wvT, 2048, 512);
  transpose_cast<<<dim3(2048 / 32, 2048 / 32), 256, 0, stream>>>(wo, woT, 2048, 2048);

  // fused Q|K|V projection (Q pre-scaled by QSCALE inside epilogue)
  gemm_bt<3><<<dim3(3072 / 128, 4096 / 128), 256, 0, stream>>>(
      xb, wqT, nullptr, Qb, Kb, Vb, 4096, 3072, 2048);

  transpose_u16<<<dim3(2048 / 32, 512 / 32, 2), 256, 0, stream>>>(Vb, VTb);

  attn_kernel<<<dim3(8, 32, 2), 256, 0, stream>>>(Qb, Kb, VTb, attn);

  gemm_bt<1><<<dim3(2048 / 128, 4096 / 128), 256, 0, stream>>>(
      attn, woT, out, nullptr, nullptr, nullptr, 4096, 2048, 2048);
}

// Round 7
// 231.130 us; speedup vs baseline: 1.1360x; 1.0326x over previous
//
#include <hip/hip_runtime.h>

typedef unsigned short u16;
typedef unsigned int u32;
typedef unsigned long long u64;

typedef __bf16 bf16x8 __attribute__((ext_vector_type(8)));
typedef float f32x4 __attribute__((ext_vector_type(4)));
typedef u16 u16x4 __attribute__((ext_vector_type(4)));

__device__ __forceinline__ u16 f2bf(float f) {
  u32 u = __builtin_bit_cast(u32, f);
  u += 0x7fffu + ((u >> 16) & 1u);
  return (u16)(u >> 16);
}

__device__ __forceinline__ u32 packbf2(float a, float b) {
  __bf16 x = (__bf16)a, y = (__bf16)b;
  return (u32)__builtin_bit_cast(u16, x) | ((u32)__builtin_bit_cast(u16, y) << 16);
}

__device__ __forceinline__ float fexp2(float x) {
#if __has_builtin(__builtin_amdgcn_exp2f)
  return __builtin_amdgcn_exp2f(x);
#else
  return exp2f(x);
#endif
}

__device__ __forceinline__ void gload_lds16(const void* g, void* lds) {
  __builtin_amdgcn_global_load_lds(
      (const __attribute__((address_space(1))) void*)g,
      (__attribute__((address_space(3))) void*)lds, 16, 0, 0);
}

// 0.125 (1/sqrt(64)) * log2(e) — folded into Q projection so softmax runs in exp2 domain
#define QSCALE 0.18033688011112043f

// ---------------- cast x: fp32 -> bf16 ----------------
__global__ __launch_bounds__(256) void cast_f32_bf16(
    const float* __restrict__ in, u16* __restrict__ out, int n4) {
  int i = (blockIdx.x * 256 + threadIdx.x) * 4;
  float4 v = *reinterpret_cast<const float4*>(in + i);
  u16x4 o;
  o[0] = f2bf(v.x); o[1] = f2bf(v.y); o[2] = f2bf(v.z); o[3] = f2bf(v.w);
  *reinterpret_cast<u16x4*>(out + i) = o;
}

// ---------------- transpose + cast: w[K][N] fp32 -> wt[N][K] bf16 ----------------
__global__ __launch_bounds__(256) void transpose_cast(
    const float* __restrict__ w, u16* __restrict__ wt, int K, int N) {
  __shared__ float tile[32][33];
  int bx = blockIdx.x * 32;  // n
  int by = blockIdx.y * 32;  // k
  int tx = threadIdx.x & 31, ty = threadIdx.x >> 5;
#pragma unroll
  for (int i = 0; i < 32; i += 8)
    tile[ty + i][tx] = w[(size_t)(by + ty + i) * N + bx + tx];
  __syncthreads();
#pragma unroll
  for (int i = 0; i < 32; i += 8)
    wt[(size_t)(bx + ty + i) * K + by + tx] = f2bf(tile[tx][ty + i]);
}

// ---------------- transpose u16: V[4096][512] -> VT[B*512][2048] ----------------
__global__ __launch_bounds__(256) void transpose_u16(
    const u16* __restrict__ in, u16* __restrict__ out) {
  __shared__ u16 tile[32][33];
  int bx = blockIdx.x * 32;  // t dim
  int by = blockIdx.y * 32;  // col dim
  int bz = blockIdx.z;       // batch
  int tx = threadIdx.x & 31, ty = threadIdx.x >> 5;
#pragma unroll
  for (int i = 0; i < 32; i += 8)
    tile[ty + i][tx] = in[((size_t)bz * 2048 + bx + ty + i) * 512 + by + tx];
  __syncthreads();
#pragma unroll
  for (int i = 0; i < 32; i += 8)
    out[((size_t)bz * 512 + by + ty + i) * 2048 + bx + tx] = tile[tx][ty + i];
}

// ---------------- GEMM: C[M][N] = A[M][K](bf16) * BT[N][K](bf16) ----------------
// 128x128 tile, BK=32, 4 waves (best grid-fill at these shapes; 256^2 starves
// the grid — R5 regression).
// MODE 1: f32 out (ld=N). MODE 3: fused QKV split — cols [0,2048) -> Cb (Q, ld2048,
// scaled by QSCALE), [2048,2560) -> Cb2 (K, ld512), [2560,3072) -> Cb3 (V, ld512).
// XCD-aware bijective block swizzle (requires nwg % 8 == 0).
template <int MODE>
__global__ __launch_bounds__(256) void gemm_bt(
    const u16* __restrict__ A, const u16* __restrict__ BT,
    float* __restrict__ Cf, u16* __restrict__ Cb, u16* __restrict__ Cb2,
    u16* __restrict__ Cb3, int M, int N, int K) {
  __shared__ __align__(16) u16 As[128 * 32];
  __shared__ __align__(16) u16 Bs[128 * 32];
  const int t = threadIdx.x;
  const int lane = t & 63;
  const int w = t >> 6;
  const int wr = w >> 1, wc = w & 1;
  const int l15 = lane & 15;
  const int l4 = lane >> 4;

  // XCD swizzle: each XCD gets a contiguous chunk of the row-major tile space
  const int nwg = gridDim.x * gridDim.y;
  const int bid = blockIdx.y * gridDim.x + blockIdx.x;
  const int wg = (bid & 7) * (nwg >> 3) + (bid >> 3);
  const int brow = (wg / gridDim.x) * 128;
  const int bcol = (wg % gridDim.x) * 128;

  f32x4 acc[4][4];
#pragma unroll
  for (int m = 0; m < 4; m++)
#pragma unroll
    for (int n = 0; n < 4; n++)
#pragma unroll
      for (int r = 0; r < 4; r++) acc[m][n][r] = 0.f;

  const size_t Arow0 = (size_t)brow * K;
  const size_t Brow0 = (size_t)bcol * K;

  for (int kk = 0; kk < K; kk += 32) {
#pragma unroll
    for (int c = 0; c < 2; ++c) {
      int chunk = c * 256 + t;
      int row = chunk >> 2;
      int col = (chunk & 3) * 8;
      gload_lds16(&A[Arow0 + (size_t)row * K + kk + col], &As[chunk * 8]);
      gload_lds16(&BT[Brow0 + (size_t)row * K + kk + col], &Bs[chunk * 8]);
    }
    __syncthreads();
    const int k0 = l4 * 8;
    bf16x8 a[4], b[4];
#pragma unroll
    for (int m = 0; m < 4; m++)
      a[m] = *reinterpret_cast<const bf16x8*>(&As[(wr * 64 + m * 16 + l15) * 32 + k0]);
#pragma unroll
    for (int n = 0; n < 4; n++)
      b[n] = *reinterpret_cast<const bf16x8*>(&Bs[(wc * 64 + n * 16 + l15) * 32 + k0]);
#pragma unroll
    for (int m = 0; m < 4; m++)
#pragma unroll
      for (int n = 0; n < 4; n++)
        acc[m][n] = __builtin_amdgcn_mfma_f32_16x16x32_bf16(a[m], b[n], acc[m][n], 0, 0, 0);
    __syncthreads();
  }

#pragma unroll
  for (int m = 0; m < 4; m++) {
    int grow0 = brow + wr * 64 + m * 16 + l4 * 4;
#pragma unroll
    for (int n = 0; n < 4; n++) {
      int gcol = bcol + wc * 64 + n * 16 + l15;
#pragma unroll
      for (int r = 0; r < 4; r++) {
        if (MODE == 1) {
          Cf[(size_t)(grow0 + r) * N + gcol] = acc[m][n][r];
        } else {  // MODE 3 — bcol is 128-aligned so whole block is in one region
          if (bcol < 2048)
            Cb[(size_t)(grow0 + r) * 2048 + gcol] = f2bf(acc[m][n][r] * QSCALE);
          else if (bcol < 2560)
            Cb2[(size_t)(grow0 + r) * 512 + (gcol - 2048)] = f2bf(acc[m][n][r]);
          else
            Cb3[(size_t)(grow0 + r) * 512 + (gcol - 2560)] = f2bf(acc[m][n][r]);
        }
      }
    }
  }
}

// ---------------- flash attention v6 (causal, GQA, swapped QK^T) ----------------
// Occupancy-first restructure: QBLK=64, grid (16,32,2)=1024 blocks, 4 waves of
// 16 q-rows, LDS 40KB -> 4 blocks/CU = 16 waves/CU (2x the v4/v5 cap, which the
// R6 null showed was the real limiter: all pipes <50%, latency-bound at 2/SIMD).
// Block jj processes q-tile (31-jj) then jj -> 33 kv steps uniformly.
// Swapped mfma(K,Q): lane (g=l>>4, q=l&15) holds S^T[kv = c*16+g*4+r][q].
__global__ __launch_bounds__(256, 4) void attn_kernel(
    const u16* __restrict__ Qb, const u16* __restrict__ Kb,
    const u16* __restrict__ VT, u16* __restrict__ Ob) {
  const int jj = blockIdx.x;  // 0..15
  const int h = blockIdx.y, b = blockIdx.z;
  const int kvh = h >> 2;
  const int t = threadIdx.x;
  const int lane = t & 63;
  const int w = t >> 6;
  const int q15 = lane & 15, g = lane >> 4;

  __shared__ __align__(16) u16 Ks[2][64 * 64];
  __shared__ __align__(16) u16 Vs[2][64 * 64];  // V^T tile: [d][kv]
  __shared__ __align__(16) u32 Pu[4][16 * 32];  // per-wave P / epilogue buffer

  const size_t Krow0 = (size_t)b * 2048;
  const size_t Vrow0 = ((size_t)b * 8 + kvh) * 64;

  auto stage = [&](int buf, int kvbase) {
#pragma unroll
    for (int c = 0; c < 2; ++c) {
      int chunk = c * 256 + t;
      int row = chunk >> 3, gg = chunk & 7;
      int gcs = (gg ^ (row & 7)) * 8;
      gload_lds16(&Kb[(Krow0 + kvbase + row) * 512 + kvh * 64 + gcs],
                  &Ks[buf][chunk * 8]);
      gload_lds16(&VT[(Vrow0 + row) * 2048 + kvbase + gcs],
                  &Vs[buf][chunk * 8]);
    }
  };

  const int swzB = (q15 & 7) << 3;  // u16-unit frag-read swizzle (matches stage)
  const int swzP = (q15 & 7) << 2;  // u32-unit swizzle for Pu
  u32* const pw = &Pu[w][0];
  const int nA = 32 - jj;   // phase-A kv-steps (q-tile 31-jj)
  const int nsteps = 33;
  auto kvb_of = [&](int ss) { return ((ss < nA) ? ss : ss - nA) << 6; };

  stage(0, 0);
  __syncthreads();
  int cur = 0;
  int ss = 0;

#pragma unroll
  for (int ph = 0; ph < 2; ++ph) {
    const int qt = ph ? jj : 31 - jj;
    const int nkv = qt + 1;
    const int wq0 = qt * 64 + w * 16;

    // Q fragments — B-operand layout (row=q15, k-chunk=g*8)
    bf16x8 qf[2];
    {
      const u16* q0 = &Qb[((size_t)b * 2048 + wq0 + q15) * 2048 + h * 64 + g * 8];
      qf[0] = *reinterpret_cast<const bf16x8*>(q0);
      qf[1] = *reinterpret_cast<const bf16x8*>(q0 + 32);
    }

    f32x4 oo[4];  // O^T accum: d = c2*16+g*4+r, col q=q15
#pragma unroll
    for (int c = 0; c < 4; c++)
#pragma unroll
      for (int r = 0; r < 4; r++) oo[c][r] = 0.f;
    float mr = -1e30f, lr = 0.f;

    for (int kv = 0; kv < nkv; ++kv, ++ss) {
      const int kvbase = kv << 6;
      if (ss + 1 < nsteps) stage(cur ^ 1, kvb_of(ss + 1));

      // ---- S^T = K Q^T : D[kv][q] ----
      f32x4 s[4];
#pragma unroll
      for (int c = 0; c < 4; c++)
#pragma unroll
        for (int r = 0; r < 4; r++) s[c][r] = 0.f;
      __builtin_amdgcn_s_setprio(1);
#pragma unroll
      for (int ks = 0; ks < 2; ++ks) {
        const int kcol = (ks * 32 + g * 8) ^ swzB;
#pragma unroll
        for (int c = 0; c < 4; c++) {
          bf16x8 kb = *reinterpret_cast<const bf16x8*>(
              &Ks[cur][(c * 16 + q15) * 64 + kcol]);
          s[c] = __builtin_amdgcn_mfma_f32_16x16x32_bf16(kb, qf[ks], s[c], 0, 0, 0);
        }
      }
      __builtin_amdgcn_s_setprio(0);

      // causal mask: only the diagonal tile (kv == qt) needs it
      if (kv == qt) {
        const int qg = wq0 + q15;
#pragma unroll
        for (int c = 0; c < 4; c++)
#pragma unroll
          for (int r = 0; r < 4; r++)
            if (kvbase + c * 16 + g * 4 + r > qg) s[c][r] = -1e30f;
      }

      // softmax: in-lane max over 16, cross-g reduce (2 shfl)
      float mx0 = fmaxf(fmaxf(s[0][0], s[0][1]), fmaxf(s[0][2], s[0][3]));
      float mx1 = fmaxf(fmaxf(s[1][0], s[1][1]), fmaxf(s[1][2], s[1][3]));
      float mx2 = fmaxf(fmaxf(s[2][0], s[2][1]), fmaxf(s[2][2], s[2][3]));
      float mx3 = fmaxf(fmaxf(s[3][0], s[3][1]), fmaxf(s[3][2], s[3][3]));
      float mx = fmaxf(fmaxf(mx0, mx1), fmaxf(mx2, mx3));
      mx = fmaxf(mx, __shfl_xor(mx, 16));
      mx = fmaxf(mx, __shfl_xor(mx, 32));
      // defer-max (T13): rescale only when tile max meaningfully exceeds mr
      if (!__all(mx <= mr + 8.f)) {
        float mnew = fmaxf(mr, mx);
        float alpha = fexp2(mr - mnew);
        lr *= alpha;
#pragma unroll
        for (int c = 0; c < 4; c++)
#pragma unroll
          for (int r = 0; r < 4; r++) oo[c][r] *= alpha;
        mr = mnew;
      }
      float p[4][4];
      float rs = 0.f;
#pragma unroll
      for (int c = 0; c < 4; c++) {
        float t0 = fexp2(s[c][0] - mr);
        float t1 = fexp2(s[c][1] - mr);
        float t2 = fexp2(s[c][2] - mr);
        float t3 = fexp2(s[c][3] - mr);
        p[c][0] = t0; p[c][1] = t1; p[c][2] = t2; p[c][3] = t3;
        rs += (t0 + t1) + (t2 + t3);
      }
      rs += __shfl_xor(rs, 16);
      rs += __shfl_xor(rs, 32);
      lr += rs;
      // pack P -> per-wave LDS (b64 writes, K-style swizzle)
#pragma unroll
      for (int c = 0; c < 4; c++) {
        u64 wv = (u64)packbf2(p[c][0], p[c][1]) |
                 ((u64)packbf2(p[c][2], p[c][3]) << 32);
        *reinterpret_cast<u64*>(&pw[q15 * 32 + ((c * 8 + g * 2) ^ swzP)]) = wv;
      }
      // read back as B-fragment (row=q15, kv-chunk=g*8)
      bf16x8 pb[2];
#pragma unroll
      for (int ks = 0; ks < 2; ++ks)
        pb[ks] = *reinterpret_cast<const bf16x8*>(
            &pw[q15 * 32 + ((ks * 16 + g * 4) ^ swzP)]);

      // ---- O^T += V^T P : D[d][q] ----
      __builtin_amdgcn_s_setprio(1);
#pragma unroll
      for (int ks = 0; ks < 2; ++ks) {
        const int vcol = (ks * 32 + g * 8) ^ swzB;
#pragma unroll
        for (int c2 = 0; c2 < 4; c2++) {
          bf16x8 vb = *reinterpret_cast<const bf16x8*>(
              &Vs[cur][(c2 * 16 + q15) * 64 + vcol]);
          oo[c2] = __builtin_amdgcn_mfma_f32_16x16x32_bf16(vb, pb[ks], oo[c2], 0, 0, 0);
        }
      }
      __builtin_amdgcn_s_setprio(0);

      __syncthreads();
      cur ^= 1;
    }

    // ---- epilogue: normalize, transpose via per-wave LDS, coalesced store ----
    const int qq = lane >> 2, cl = lane & 3;
    const int swq = (qq & 7) << 2;
    {
      float rcp = 1.0f / lr;
#pragma unroll
      for (int c2 = 0; c2 < 4; c2++) {
        u64 wv = (u64)packbf2(oo[c2][0] * rcp, oo[c2][1] * rcp) |
                 ((u64)packbf2(oo[c2][2] * rcp, oo[c2][3] * rcp) << 32);
        *reinterpret_cast<u64*>(&pw[q15 * 32 + ((c2 * 8 + g * 2) ^ swzP)]) = wv;
      }
      uint4 d0 = *reinterpret_cast<const uint4*>(&pw[qq * 32 + ((cl * 4) ^ swq)]);
      uint4 d1 = *reinterpret_cast<const uint4*>(&pw[qq * 32 + ((cl * 4 + 16) ^ swq)]);
      u32* og = (u32*)Ob + ((size_t)b * 2048 + wq0 + qq) * 1024 + h * 32;
      *reinterpret_cast<uint4*>(&og[cl * 4]) = d0;
      *reinterpret_cast<uint4*>(&og[cl * 4 + 16]) = d1;
    }
  }
}

// ---------------- launcher ----------------
extern "C" void kernel_launch(void* const* d_in, const int* in_sizes, int n_in,
                              void* d_out, int out_size, void* d_ws, size_t ws_size,
                              hipStream_t stream) {
  const float* x = (const float*)d_in[0];
  const float* wq = (const float*)d_in[1];
  const float* wk = (const float*)d_in[2];
  const float* wv = (const float*)d_in[3];
  const float* wo = (const float*)d_in[4];
  float* out = (float*)d_out;

  char* p = (char*)d_ws;
  u16* xb = (u16*)p;   p += (size_t)4096 * 2048 * 2;
  u16* wqT = (u16*)p;  p += (size_t)2048 * 2048 * 2;  // wqT|wkT|wvT contiguous:
  u16* wkT = (u16*)p;  p += (size_t)512 * 2048 * 2;   //   fused QKV GEMM reads
  u16* wvT = (u16*)p;  p += (size_t)512 * 2048 * 2;   //   them as one 3072x2048 BT
  u16* woT = (u16*)p;  p += (size_t)2048 * 2048 * 2;
  u16* Qb = (u16*)p;   p += (size_t)4096 * 2048 * 2;
  u16* Kb = (u16*)p;   p += (size_t)4096 * 512 * 2;
  u16* Vb = (u16*)p;   p += (size_t)4096 * 512 * 2;
  u16* VTb = (u16*)p;  p += (size_t)2 * 512 * 2048 * 2;
  u16* attn = xb;  // reuse: x_bf16 dead after projections

  cast_f32_bf16<<<8192, 256, 0, stream>>>(x, xb, 4096 * 2048);
  transpose_cast<<<dim3(2048 / 32, 2048 / 32), 256, 0, stream>>>(wq, wqT, 2048, 2048);
  transpose_cast<<<dim3(512 / 32, 2048 / 32), 256, 0, stream>>>(wk, wkT, 2048, 512);
  transpose_cast<<<dim3(512 / 32, 2048 / 32), 256, 0, stream>>>(wv, wvT, 2048, 512);
  transpose_cast<<<dim3(2048 / 32, 2048 / 32), 256, 0, stream>>>(wo, woT, 2048, 2048);

  // fused Q|K|V projection (Q pre-scaled by QSCALE inside epilogue)
  gemm_bt<3><<<dim3(3072 / 128, 4096 / 128), 256, 0, stream>>>(
      xb, wqT, nullptr, Qb, Kb, Vb, 4096, 3072, 2048);

  transpose_u16<<<dim3(2048 / 32, 512 / 32, 2), 256, 0, stream>>>(Vb, VTb);

  attn_kernel<<<dim3(16, 32, 2), 256, 0, stream>>>(Qb, Kb, VTb, attn);

  gemm_bt<1><<<dim3(2048 / 128, 4096 / 128), 256, 0, stream>>>(
      attn, woT, out, nullptr, nullptr, nullptr, 4096, 2048, 2048);
}

// Round 8
// 209.599 us; speedup vs baseline: 1.2527x; 1.1027x over previous
//
#include <hip/hip_runtime.h>

typedef unsigned short u16;
typedef unsigned int u32;
typedef unsigned long long u64;

typedef __bf16 bf16x8 __attribute__((ext_vector_type(8)));
typedef float f32x4 __attribute__((ext_vector_type(4)));
typedef u16 u16x4 __attribute__((ext_vector_type(4)));

__device__ __forceinline__ u16 f2bf(float f) {
  u32 u = __builtin_bit_cast(u32, f);
  u += 0x7fffu + ((u >> 16) & 1u);
  return (u16)(u >> 16);
}

__device__ __forceinline__ u32 packbf2(float a, float b) {
  __bf16 x = (__bf16)a, y = (__bf16)b;
  return (u32)__builtin_bit_cast(u16, x) | ((u32)__builtin_bit_cast(u16, y) << 16);
}

__device__ __forceinline__ float fexp2(float x) {
#if __has_builtin(__builtin_amdgcn_exp2f)
  return __builtin_amdgcn_exp2f(x);
#else
  return exp2f(x);
#endif
}

__device__ __forceinline__ void gload_lds16(const void* g, void* lds) {
  __builtin_amdgcn_global_load_lds(
      (const __attribute__((address_space(1))) void*)g,
      (__attribute__((address_space(3))) void*)lds, 16, 0, 0);
}

// 0.125 (1/sqrt(64)) * log2(e) — folded into Q projection so softmax runs in exp2 domain
#define QSCALE 0.18033688011112043f

// ---------------- cast x: fp32 -> bf16 ----------------
__global__ __launch_bounds__(256) void cast_f32_bf16(
    const float* __restrict__ in, u16* __restrict__ out, int n4) {
  int i = (blockIdx.x * 256 + threadIdx.x) * 4;
  float4 v = *reinterpret_cast<const float4*>(in + i);
  u16x4 o;
  o[0] = f2bf(v.x); o[1] = f2bf(v.y); o[2] = f2bf(v.z); o[3] = f2bf(v.w);
  *reinterpret_cast<u16x4*>(out + i) = o;
}

// ---------------- fused transpose+cast for all 4 weights (K=2048 rows) --------
// z=0: wq(2048 cols), z=1: wo(2048), z=2: wk(512), z=3: wv(512)
__global__ __launch_bounds__(256) void transpose_cast_all(
    const float* __restrict__ wq, const float* __restrict__ wk,
    const float* __restrict__ wv, const float* __restrict__ wo,
    u16* __restrict__ wqT, u16* __restrict__ wkT,
    u16* __restrict__ wvT, u16* __restrict__ woT) {
  constexpr int K = 2048;
  const float* w_;
  u16* wt;
  int N;
  switch (blockIdx.z) {
    case 0: w_ = wq; wt = wqT; N = 2048; break;
    case 1: w_ = wo; wt = woT; N = 2048; break;
    case 2: w_ = wk; wt = wkT; N = 512; break;
    default: w_ = wv; wt = wvT; N = 512; break;
  }
  int bx = blockIdx.x * 32;  // n
  if (bx >= N) return;
  int by = blockIdx.y * 32;  // k
  __shared__ float tile[32][33];
  int tx = threadIdx.x & 31, ty = threadIdx.x >> 5;
#pragma unroll
  for (int i = 0; i < 32; i += 8)
    tile[ty + i][tx] = w_[(size_t)(by + ty + i) * N + bx + tx];
  __syncthreads();
#pragma unroll
  for (int i = 0; i < 32; i += 8)
    wt[(size_t)(bx + ty + i) * K + by + tx] = f2bf(tile[tx][ty + i]);
}

// ---------------- transpose u16: V[4096][512] -> VT[B*512][2048] ----------------
__global__ __launch_bounds__(256) void transpose_u16(
    const u16* __restrict__ in, u16* __restrict__ out) {
  __shared__ u16 tile[32][33];
  int bx = blockIdx.x * 32;  // t dim
  int by = blockIdx.y * 32;  // col dim
  int bz = blockIdx.z;       // batch
  int tx = threadIdx.x & 31, ty = threadIdx.x >> 5;
#pragma unroll
  for (int i = 0; i < 32; i += 8)
    tile[ty + i][tx] = in[((size_t)bz * 2048 + bx + ty + i) * 512 + by + tx];
  __syncthreads();
#pragma unroll
  for (int i = 0; i < 32; i += 8)
    out[((size_t)bz * 512 + by + ty + i) * 2048 + bx + tx] = tile[tx][ty + i];
}

// ---------------- GEMM: C[M][N] = A[M][K](bf16) * BT[N][K](bf16), K=2048 -------
// 128x128 tile, BK=64 (32 barrier-pairs instead of 64), 4 waves.
// T2 XOR-swizzle on LDS (pre-swizzled global source + swizzled ds_read):
// without it, 128B rows make b128 frag reads a 32-way bank conflict.
// MODE 1: f32 out (ld=N). MODE 3: fused QKV split — cols [0,2048) -> Cb (Q,
// ld2048, scaled by QSCALE), [2048,2560) -> Cb2 (K, ld512), [2560,3072) -> Cb3.
// XCD-aware bijective block swizzle (requires nwg % 8 == 0).
template <int MODE>
__global__ __launch_bounds__(256) void gemm_bt(
    const u16* __restrict__ A, const u16* __restrict__ BT,
    float* __restrict__ Cf, u16* __restrict__ Cb, u16* __restrict__ Cb2,
    u16* __restrict__ Cb3, int M, int N) {
  constexpr int K = 2048;
  __shared__ __align__(16) u16 As[128 * 64];
  __shared__ __align__(16) u16 Bs[128 * 64];
  const int t = threadIdx.x;
  const int lane = t & 63;
  const int w = t >> 6;
  const int wr = w >> 1, wc = w & 1;
  const int l15 = lane & 15;
  const int l4 = lane >> 4;

  // XCD swizzle: each XCD gets a contiguous chunk of the row-major tile space
  const int nwg = gridDim.x * gridDim.y;
  const int bid = blockIdx.y * gridDim.x + blockIdx.x;
  const int wg = (bid & 7) * (nwg >> 3) + (bid >> 3);
  const int brow = (wg / gridDim.x) * 128;
  const int bcol = (wg % gridDim.x) * 128;

  f32x4 acc[4][4];
#pragma unroll
  for (int m = 0; m < 4; m++)
#pragma unroll
    for (int n = 0; n < 4; n++)
#pragma unroll
      for (int r = 0; r < 4; r++) acc[m][n][r] = 0.f;

  // staging: thread t owns rows r0+32c (c=0..3), granule (t&7), source column
  // pre-swizzled so linear LDS dest == XOR-swizzled layout
  const int r0 = t >> 3;
  const int gcs = ((t & 7) ^ (r0 & 7)) * 8;  // per-thread constant
  const u16* pa = A + (size_t)(brow + r0) * K + gcs;
  const u16* pb = BT + (size_t)(bcol + r0) * K + gcs;
  u16* const la = &As[t * 8];
  u16* const lb = &Bs[t * 8];

  for (int kk = 0; kk < K; kk += 64) {
#pragma unroll
    for (int c = 0; c < 4; ++c) {
      gload_lds16(pa + (size_t)c * 32 * K, la + c * 2048);
      gload_lds16(pb + (size_t)c * 32 * K, lb + c * 2048);
    }
    pa += 64;
    pb += 64;
    __syncthreads();
#pragma unroll
    for (int ks2 = 0; ks2 < 2; ++ks2) {
      bf16x8 a[4], b[4];
#pragma unroll
      for (int m = 0; m < 4; m++) {
        int row = wr * 64 + m * 16 + l15;
        a[m] = *reinterpret_cast<const bf16x8*>(
            &As[row * 64 + (((ks2 * 4 + l4) ^ (row & 7)) * 8)]);
      }
#pragma unroll
      for (int n = 0; n < 4; n++) {
        int row = wc * 64 + n * 16 + l15;
        b[n] = *reinterpret_cast<const bf16x8*>(
            &Bs[row * 64 + (((ks2 * 4 + l4) ^ (row & 7)) * 8)]);
      }
#pragma unroll
      for (int m = 0; m < 4; m++)
#pragma unroll
        for (int n = 0; n < 4; n++)
          acc[m][n] = __builtin_amdgcn_mfma_f32_16x16x32_bf16(a[m], b[n], acc[m][n], 0, 0, 0);
    }
    __syncthreads();
  }

#pragma unroll
  for (int m = 0; m < 4; m++) {
    int grow0 = brow + wr * 64 + m * 16 + l4 * 4;
#pragma unroll
    for (int n = 0; n < 4; n++) {
      int gcol = bcol + wc * 64 + n * 16 + l15;
#pragma unroll
      for (int r = 0; r < 4; r++) {
        if (MODE == 1) {
          Cf[(size_t)(grow0 + r) * N + gcol] = acc[m][n][r];
        } else {  // MODE 3 — bcol is 128-aligned so whole block is in one region
          if (bcol < 2048)
            Cb[(size_t)(grow0 + r) * 2048 + gcol] = f2bf(acc[m][n][r] * QSCALE);
          else if (bcol < 2560)
            Cb2[(size_t)(grow0 + r) * 512 + (gcol - 2048)] = f2bf(acc[m][n][r]);
          else
            Cb3[(size_t)(grow0 + r) * 512 + (gcol - 2560)] = f2bf(acc[m][n][r]);
        }
      }
    }
  }
}

// ---------------- flash attention v6 (causal, GQA, swapped QK^T) ----------------
// QBLK=64, grid (16,32,2)=1024 blocks, 4 waves of 16 q-rows, LDS 40KB ->
// 4 blocks/CU = 16 waves/CU. Block jj: q-tile (31-jj) then jj -> 33 steps.
// Swapped mfma(K,Q): lane (g=l>>4, q=l&15) holds S^T[kv = c*16+g*4+r][q].
__global__ __launch_bounds__(256, 4) void attn_kernel(
    const u16* __restrict__ Qb, const u16* __restrict__ Kb,
    const u16* __restrict__ VT, u16* __restrict__ Ob) {
  const int jj = blockIdx.x;  // 0..15
  const int h = blockIdx.y, b = blockIdx.z;
  const int kvh = h >> 2;
  const int t = threadIdx.x;
  const int lane = t & 63;
  const int w = t >> 6;
  const int q15 = lane & 15, g = lane >> 4;

  __shared__ __align__(16) u16 Ks[2][64 * 64];
  __shared__ __align__(16) u16 Vs[2][64 * 64];  // V^T tile: [d][kv]
  __shared__ __align__(16) u32 Pu[4][16 * 32];  // per-wave P / epilogue buffer

  const size_t Krow0 = (size_t)b * 2048;
  const size_t Vrow0 = ((size_t)b * 8 + kvh) * 64;

  auto stage = [&](int buf, int kvbase) {
#pragma unroll
    for (int c = 0; c < 2; ++c) {
      int chunk = c * 256 + t;
      int row = chunk >> 3, gg = chunk & 7;
      int gcs = (gg ^ (row & 7)) * 8;
      gload_lds16(&Kb[(Krow0 + kvbase + row) * 512 + kvh * 64 + gcs],
                  &Ks[buf][chunk * 8]);
      gload_lds16(&VT[(Vrow0 + row) * 2048 + kvbase + gcs],
                  &Vs[buf][chunk * 8]);
    }
  };

  const int swzB = (q15 & 7) << 3;  // u16-unit frag-read swizzle (matches stage)
  const int swzP = (q15 & 7) << 2;  // u32-unit swizzle for Pu
  u32* const pw = &Pu[w][0];
  const int nA = 32 - jj;   // phase-A kv-steps (q-tile 31-jj)
  const int nsteps = 33;
  auto kvb_of = [&](int ss) { return ((ss < nA) ? ss : ss - nA) << 6; };

  stage(0, 0);
  __syncthreads();
  int cur = 0;
  int ss = 0;

#pragma unroll
  for (int ph = 0; ph < 2; ++ph) {
    const int qt = ph ? jj : 31 - jj;
    const int nkv = qt + 1;
    const int wq0 = qt * 64 + w * 16;

    // Q fragments — B-operand layout (row=q15, k-chunk=g*8)
    bf16x8 qf[2];
    {
      const u16* q0 = &Qb[((size_t)b * 2048 + wq0 + q15) * 2048 + h * 64 + g * 8];
      qf[0] = *reinterpret_cast<const bf16x8*>(q0);
      qf[1] = *reinterpret_cast<const bf16x8*>(q0 + 32);
    }

    f32x4 oo[4];  // O^T accum: d = c2*16+g*4+r, col q=q15
#pragma unroll
    for (int c = 0; c < 4; c++)
#pragma unroll
      for (int r = 0; r < 4; r++) oo[c][r] = 0.f;
    float mr = -1e30f, lr = 0.f;

    for (int kv = 0; kv < nkv; ++kv, ++ss) {
      const int kvbase = kv << 6;
      if (ss + 1 < nsteps) stage(cur ^ 1, kvb_of(ss + 1));

      // ---- S^T = K Q^T : D[kv][q] ----
      f32x4 s[4];
#pragma unroll
      for (int c = 0; c < 4; c++)
#pragma unroll
        for (int r = 0; r < 4; r++) s[c][r] = 0.f;
      __builtin_amdgcn_s_setprio(1);
#pragma unroll
      for (int ks = 0; ks < 2; ++ks) {
        const int kcol = (ks * 32 + g * 8) ^ swzB;
#pragma unroll
        for (int c = 0; c < 4; c++) {
          bf16x8 kb = *reinterpret_cast<const bf16x8*>(
              &Ks[cur][(c * 16 + q15) * 64 + kcol]);
          s[c] = __builtin_amdgcn_mfma_f32_16x16x32_bf16(kb, qf[ks], s[c], 0, 0, 0);
        }
      }
      __builtin_amdgcn_s_setprio(0);

      // causal mask: only the diagonal tile (kv == qt) needs it
      if (kv == qt) {
        const int qg = wq0 + q15;
#pragma unroll
        for (int c = 0; c < 4; c++)
#pragma unroll
          for (int r = 0; r < 4; r++)
            if (kvbase + c * 16 + g * 4 + r > qg) s[c][r] = -1e30f;
      }

      // softmax: in-lane max over 16, cross-g reduce (2 shfl)
      float mx0 = fmaxf(fmaxf(s[0][0], s[0][1]), fmaxf(s[0][2], s[0][3]));
      float mx1 = fmaxf(fmaxf(s[1][0], s[1][1]), fmaxf(s[1][2], s[1][3]));
      float mx2 = fmaxf(fmaxf(s[2][0], s[2][1]), fmaxf(s[2][2], s[2][3]));
      float mx3 = fmaxf(fmaxf(s[3][0], s[3][1]), fmaxf(s[3][2], s[3][3]));
      float mx = fmaxf(fmaxf(mx0, mx1), fmaxf(mx2, mx3));
      mx = fmaxf(mx, __shfl_xor(mx, 16));
      mx = fmaxf(mx, __shfl_xor(mx, 32));
      // defer-max (T13): rescale only when tile max meaningfully exceeds mr
      if (!__all(mx <= mr + 8.f)) {
        float mnew = fmaxf(mr, mx);
        float alpha = fexp2(mr - mnew);
        lr *= alpha;
#pragma unroll
        for (int c = 0; c < 4; c++)
#pragma unroll
          for (int r = 0; r < 4; r++) oo[c][r] *= alpha;
        mr = mnew;
      }
      float p[4][4];
      float rs = 0.f;
#pragma unroll
      for (int c = 0; c < 4; c++) {
        float t0 = fexp2(s[c][0] - mr);
        float t1 = fexp2(s[c][1] - mr);
        float t2 = fexp2(s[c][2] - mr);
        float t3 = fexp2(s[c][3] - mr);
        p[c][0] = t0; p[c][1] = t1; p[c][2] = t2; p[c][3] = t3;
        rs += (t0 + t1) + (t2 + t3);
      }
      rs += __shfl_xor(rs, 16);
      rs += __shfl_xor(rs, 32);
      lr += rs;
      // pack P -> per-wave LDS (b64 writes, K-style swizzle)
#pragma unroll
      for (int c = 0; c < 4; c++) {
        u64 wv = (u64)packbf2(p[c][0], p[c][1]) |
                 ((u64)packbf2(p[c][2], p[c][3]) << 32);
        *reinterpret_cast<u64*>(&pw[q15 * 32 + ((c * 8 + g * 2) ^ swzP)]) = wv;
      }
      // read back as B-fragment (row=q15, kv-chunk=g*8)
      bf16x8 pb[2];
#pragma unroll
      for (int ks = 0; ks < 2; ++ks)
        pb[ks] = *reinterpret_cast<const bf16x8*>(
            &pw[q15 * 32 + ((ks * 16 + g * 4) ^ swzP)]);

      // ---- O^T += V^T P : D[d][q] ----
      __builtin_amdgcn_s_setprio(1);
#pragma unroll
      for (int ks = 0; ks < 2; ++ks) {
        const int vcol = (ks * 32 + g * 8) ^ swzB;
#pragma unroll
        for (int c2 = 0; c2 < 4; c2++) {
          bf16x8 vb = *reinterpret_cast<const bf16x8*>(
              &Vs[cur][(c2 * 16 + q15) * 64 + vcol]);
          oo[c2] = __builtin_amdgcn_mfma_f32_16x16x32_bf16(vb, pb[ks], oo[c2], 0, 0, 0);
        }
      }
      __builtin_amdgcn_s_setprio(0);

      __syncthreads();
      cur ^= 1;
    }

    // ---- epilogue: normalize, transpose via per-wave LDS, coalesced store ----
    const int qq = lane >> 2, cl = lane & 3;
    const int swq = (qq & 7) << 2;
    {
      float rcp = 1.0f / lr;
#pragma unroll
      for (int c2 = 0; c2 < 4; c2++) {
        u64 wv = (u64)packbf2(oo[c2][0] * rcp, oo[c2][1] * rcp) |
                 ((u64)packbf2(oo[c2][2] * rcp, oo[c2][3] * rcp) << 32);
        *reinterpret_cast<u64*>(&pw[q15 * 32 + ((c2 * 8 + g * 2) ^ swzP)]) = wv;
      }
      uint4 d0 = *reinterpret_cast<const uint4*>(&pw[qq * 32 + ((cl * 4) ^ swq)]);
      uint4 d1 = *reinterpret_cast<const uint4*>(&pw[qq * 32 + ((cl * 4 + 16) ^ swq)]);
      u32* og = (u32*)Ob + ((size_t)b * 2048 + wq0 + qq) * 1024 + h * 32;
      *reinterpret_cast<uint4*>(&og[cl * 4]) = d0;
      *reinterpret_cast<uint4*>(&og[cl * 4 + 16]) = d1;
    }
  }
}

// ---------------- launcher ----------------
extern "C" void kernel_launch(void* const* d_in, const int* in_sizes, int n_in,
                              void* d_out, int out_size, void* d_ws, size_t ws_size,
                              hipStream_t stream) {
  const float* x = (const float*)d_in[0];
  const float* wq = (const float*)d_in[1];
  const float* wk = (const float*)d_in[2];
  const float* wv = (const float*)d_in[3];
  const float* wo = (const float*)d_in[4];
  float* out = (float*)d_out;

  char* p = (char*)d_ws;
  u16* xb = (u16*)p;   p += (size_t)4096 * 2048 * 2;
  u16* wqT = (u16*)p;  p += (size_t)2048 * 2048 * 2;  // wqT|wkT|wvT contiguous:
  u16* wkT = (u16*)p;  p += (size_t)512 * 2048 * 2;   //   fused QKV GEMM reads
  u16* wvT = (u16*)p;  p += (size_t)512 * 2048 * 2;   //   them as one 3072x2048 BT
  u16* woT = (u16*)p;  p += (size_t)2048 * 2048 * 2;
  u16* Qb = (u16*)p;   p += (size_t)4096 * 2048 * 2;
  u16* Kb = (u16*)p;   p += (size_t)4096 * 512 * 2;
  u16* Vb = (u16*)p;   p += (size_t)4096 * 512 * 2;
  u16* VTb = (u16*)p;  p += (size_t)2 * 512 * 2048 * 2;
  u16* attn = xb;  // reuse: x_bf16 dead after projections

  cast_f32_bf16<<<8192, 256, 0, stream>>>(x, xb, 4096 * 2048);
  transpose_cast_all<<<dim3(64, 64, 4), 256, 0, stream>>>(
      wq, wk, wv, wo, wqT, wkT, wvT, woT);

  // fused Q|K|V projection (Q pre-scaled by QSCALE inside epilogue)
  gemm_bt<3><<<dim3(3072 / 128, 4096 / 128), 256, 0, stream>>>(
      xb, wqT, nullptr, Qb, Kb, Vb, 4096, 3072);

  transpose_u16<<<dim3(2048 / 32, 512 / 32, 2), 256, 0, stream>>>(Vb, VTb);

  attn_kernel<<<dim3(16, 32, 2), 256, 0, stream>>>(Qb, Kb, VTb, attn);

  gemm_bt<1><<<dim3(2048 / 128, 4096 / 128), 256, 0, stream>>>(
      attn, woT, out, nullptr, nullptr, nullptr, 4096, 2048);
}

// Round 9
// 198.694 us; speedup vs baseline: 1.3215x; 1.0549x over previous
//
#include <hip/hip_runtime.h>

typedef unsigned short u16;
typedef unsigned int u32;
typedef unsigned long long u64;

typedef __bf16 bf16x8 __attribute__((ext_vector_type(8)));
typedef float f32x4 __attribute__((ext_vector_type(4)));
typedef u16 u16x4 __attribute__((ext_vector_type(4)));

__device__ __forceinline__ u16 f2bf(float f) {
  u32 u = __builtin_bit_cast(u32, f);
  u += 0x7fffu + ((u >> 16) & 1u);
  return (u16)(u >> 16);
}

__device__ __forceinline__ u32 packbf2(float a, float b) {
  __bf16 x = (__bf16)a, y = (__bf16)b;
  return (u32)__builtin_bit_cast(u16, x) | ((u32)__builtin_bit_cast(u16, y) << 16);
}

__device__ __forceinline__ float fexp2(float x) {
#if __has_builtin(__builtin_amdgcn_exp2f)
  return __builtin_amdgcn_exp2f(x);
#else
  return exp2f(x);
#endif
}

__device__ __forceinline__ void gload_lds16(const void* g, void* lds) {
  __builtin_amdgcn_global_load_lds(
      (const __attribute__((address_space(1))) void*)g,
      (__attribute__((address_space(3))) void*)lds, 16, 0, 0);
}

// 0.125 (1/sqrt(64)) * log2(e) — folded into Q projection so softmax runs in exp2 domain
#define QSCALE 0.18033688011112043f

// ---------------- cast x: fp32 -> bf16 ----------------
__global__ __launch_bounds__(256) void cast_f32_bf16(
    const float* __restrict__ in, u16* __restrict__ out, int n4) {
  int i = (blockIdx.x * 256 + threadIdx.x) * 4;
  float4 v = *reinterpret_cast<const float4*>(in + i);
  u16x4 o;
  o[0] = f2bf(v.x); o[1] = f2bf(v.y); o[2] = f2bf(v.z); o[3] = f2bf(v.w);
  *reinterpret_cast<u16x4*>(out + i) = o;
}

// ---------------- fused transpose+cast for all 4 weights (K=2048 rows) --------
__global__ __launch_bounds__(256) void transpose_cast_all(
    const float* __restrict__ wq, const float* __restrict__ wk,
    const float* __restrict__ wv, const float* __restrict__ wo,
    u16* __restrict__ wqT, u16* __restrict__ wkT,
    u16* __restrict__ wvT, u16* __restrict__ woT) {
  constexpr int K = 2048;
  const float* w_;
  u16* wt;
  int N;
  switch (blockIdx.z) {
    case 0: w_ = wq; wt = wqT; N = 2048; break;
    case 1: w_ = wo; wt = woT; N = 2048; break;
    case 2: w_ = wk; wt = wkT; N = 512; break;
    default: w_ = wv; wt = wvT; N = 512; break;
  }
  int bx = blockIdx.x * 32;  // n
  if (bx >= N) return;
  int by = blockIdx.y * 32;  // k
  __shared__ float tile[32][33];
  int tx = threadIdx.x & 31, ty = threadIdx.x >> 5;
#pragma unroll
  for (int i = 0; i < 32; i += 8)
    tile[ty + i][tx] = w_[(size_t)(by + ty + i) * N + bx + tx];
  __syncthreads();
#pragma unroll
  for (int i = 0; i < 32; i += 8)
    wt[(size_t)(bx + ty + i) * K + by + tx] = f2bf(tile[tx][ty + i]);
}

// ---------------- transpose u16: V[4096][512] -> VT[B*512][2048] ----------------
__global__ __launch_bounds__(256) void transpose_u16(
    const u16* __restrict__ in, u16* __restrict__ out) {
  __shared__ u16 tile[32][33];
  int bx = blockIdx.x * 32;  // t dim
  int by = blockIdx.y * 32;  // col dim
  int bz = blockIdx.z;       // batch
  int tx = threadIdx.x & 31, ty = threadIdx.x >> 5;
#pragma unroll
  for (int i = 0; i < 32; i += 8)
    tile[ty + i][tx] = in[((size_t)bz * 2048 + bx + ty + i) * 512 + by + tx];
  __syncthreads();
#pragma unroll
  for (int i = 0; i < 32; i += 8)
    out[((size_t)bz * 512 + by + ty + i) * 2048 + bx + tx] = tile[tx][ty + i];
}

// ---------------- GEMM 256x256, BK=64, 8 waves, 4-phase counted-vmcnt pipeline --
// C[M][N] = A[M][K](bf16)*BT[N][K](bf16), K=2048, 32 K-tiles, LDS dbuf 128KB.
// Per K-tile t (buf q=t&1), 4 phases x {issue | s_barrier | 16 MFMA | s_barrier}:
//  P1: ds_read A-mlo(8 b128)+B-nlo(4) | stage B-half0(t+1 -> q^1) | MFMA mlo x nlo
//  P2: ds_read A-mhi(8)+B-nhi(4)      | stage B-half1(t+1 -> q^1) | MFMA mlo x nhi
//  P3:                                 | stage A-half0(t+2 -> q)   | MFMA mhi x nlo
//  P4:                                 | stage A-half1(t+2 -> q)   | MFMA mhi x nhi
//      + s_waitcnt vmcnt(4) (vmcnt(0) only in the 2-tile tail)
// Race-freedom: every stage-issue is barrier-ordered after its LDS region's last
// read (A-halves of buf q are only read in P1/P2 of tile t; B-halves of buf q^1
// were last read in P1/P2 of tile t-1). Every read is gated by the previous
// tile's vmcnt(4), which retires all but the 2 newest staged halves.
template <int MODE>
__global__ __launch_bounds__(512, 2) void gemm256(
    const u16* __restrict__ A, const u16* __restrict__ BT,
    float* __restrict__ Cf, u16* __restrict__ Cb, u16* __restrict__ Cb2,
    u16* __restrict__ Cb3, int M, int N) {
  constexpr int K = 2048, NT = 32;
  __shared__ __align__(16) u16 Ab[2][256 * 64];
  __shared__ __align__(16) u16 Bb[2][256 * 64];
  const int t = threadIdx.x;
  const int lane = t & 63;
  const int w = t >> 6;
  const int wm = w >> 2, wn = w & 3;  // 2M x 4N waves; per-wave out 128x64
  const int l15 = lane & 15, l4 = lane >> 4;

  // XCD-aware bijective swizzle (nwg % 8 == 0)
  const int nwg = gridDim.x * gridDim.y;
  const int bid = blockIdx.y * gridDim.x + blockIdx.x;
  const int wg = (bid & 7) * (nwg >> 3) + (bid >> 3);
  const int brow = (wg / gridDim.x) * 256;
  const int bcol = (wg % gridDim.x) * 256;

  // staging: thread covers rows r0 and r0+64 of a 128-row half, 16B granule,
  // source column pre-swizzled so linear LDS dest == XOR-swizzled layout
  const int r0 = t >> 3;
  const int gc = ((t & 7) ^ (r0 & 7)) * 8;
  auto stageA = [&](int q, int h, int kt) {
    const u16* src = A + (size_t)(brow + h * 128 + r0) * K + kt * 64 + gc;
    u16* dst = &Ab[q][(h * 128 + r0) * 64 + (t & 7) * 8];
    gload_lds16(src, dst);
    gload_lds16(src + (size_t)64 * K, dst + 64 * 64);
  };
  auto stageB = [&](int q, int h, int kt) {
    const u16* src = BT + (size_t)(bcol + h * 128 + r0) * K + kt * 64 + gc;
    u16* dst = &Bb[q][(h * 128 + r0) * 64 + (t & 7) * 8];
    gload_lds16(src, dst);
    gload_lds16(src + (size_t)64 * K, dst + 64 * 64);
  };

  f32x4 acc[8][4];
#pragma unroll
  for (int mi = 0; mi < 8; mi++)
#pragma unroll
    for (int n = 0; n < 4; n++)
#pragma unroll
      for (int r = 0; r < 4; r++) acc[mi][n][r] = 0.f;

  // prologue: tile0 all 4 halves + tile1's A halves; retire tile0 (leave 4 in flight)
  stageA(0, 0, 0); stageA(0, 1, 0);
  stageB(0, 0, 0); stageB(0, 1, 0);
  stageA(1, 0, 1); stageA(1, 1, 1);
  asm volatile("s_waitcnt vmcnt(4)" ::: "memory");
  __builtin_amdgcn_sched_barrier(0);
  __builtin_amdgcn_s_barrier();

  for (int kt = 0; kt < NT; ++kt) {
    const int q = kt & 1;
    const u16* Al = Ab[q];
    const u16* Bl = Bb[q];
    bf16x8 af[8][2], bf[4][2];

    // ---- P1: reads A m0-3 + B n0-1 | stage B-half0(t+1) | MFMA mlo x nlo ----
#pragma unroll
    for (int m = 0; m < 4; ++m) {
      int row = wm * 128 + m * 16 + l15;
#pragma unroll
      for (int ks = 0; ks < 2; ++ks)
        af[m][ks] = *reinterpret_cast<const bf16x8*>(
            &Al[row * 64 + (((ks * 4 + l4) ^ (row & 7)) * 8)]);
    }
#pragma unroll
    for (int n = 0; n < 2; ++n) {
      int row = wn * 64 + n * 16 + l15;
#pragma unroll
      for (int ks = 0; ks < 2; ++ks)
        bf[n][ks] = *reinterpret_cast<const bf16x8*>(
            &Bl[row * 64 + (((ks * 4 + l4) ^ (row & 7)) * 8)]);
    }
    if (kt + 1 < NT) stageB(q ^ 1, 0, kt + 1);
    __builtin_amdgcn_s_barrier();
    __builtin_amdgcn_s_setprio(1);
#pragma unroll
    for (int ks = 0; ks < 2; ++ks)
#pragma unroll
      for (int m = 0; m < 4; ++m)
#pragma unroll
        for (int n = 0; n < 2; ++n)
          acc[m][n] = __builtin_amdgcn_mfma_f32_16x16x32_bf16(
              af[m][ks], bf[n][ks], acc[m][n], 0, 0, 0);
    __builtin_amdgcn_s_setprio(0);
    __builtin_amdgcn_s_barrier();

    // ---- P2: reads A m4-7 + B n2-3 | stage B-half1(t+1) | MFMA mlo x nhi ----
#pragma unroll
    for (int m = 4; m < 8; ++m) {
      int row = wm * 128 + m * 16 + l15;
#pragma unroll
      for (int ks = 0; ks < 2; ++ks)
        af[m][ks] = *reinterpret_cast<const bf16x8*>(
            &Al[row * 64 + (((ks * 4 + l4) ^ (row & 7)) * 8)]);
    }
#pragma unroll
    for (int n = 2; n < 4; ++n) {
      int row = wn * 64 + n * 16 + l15;
#pragma unroll
      for (int ks = 0; ks < 2; ++ks)
        bf[n][ks] = *reinterpret_cast<const bf16x8*>(
            &Bl[row * 64 + (((ks * 4 + l4) ^ (row & 7)) * 8)]);
    }
    if (kt + 1 < NT) stageB(q ^ 1, 1, kt + 1);
    __builtin_amdgcn_s_barrier();
    __builtin_amdgcn_s_setprio(1);
#pragma unroll
    for (int ks = 0; ks < 2; ++ks)
#pragma unroll
      for (int m = 0; m < 4; ++m)
#pragma unroll
        for (int n = 2; n < 4; ++n)
          acc[m][n] = __builtin_amdgcn_mfma_f32_16x16x32_bf16(
              af[m][ks], bf[n][ks], acc[m][n], 0, 0, 0);
    __builtin_amdgcn_s_setprio(0);
    __builtin_amdgcn_s_barrier();

    // ---- P3: stage A-half0(t+2) | MFMA mhi x nlo ----
    if (kt + 2 < NT) stageA(q, 0, kt + 2);
    __builtin_amdgcn_s_barrier();
    __builtin_amdgcn_s_setprio(1);
#pragma unroll
    for (int ks = 0; ks < 2; ++ks)
#pragma unroll
      for (int m = 4; m < 8; ++m)
#pragma unroll
        for (int n = 0; n < 2; ++n)
          acc[m][n] = __builtin_amdgcn_mfma_f32_16x16x32_bf16(
              af[m][ks], bf[n][ks], acc[m][n], 0, 0, 0);
    __builtin_amdgcn_s_setprio(0);
    __builtin_amdgcn_s_barrier();

    // ---- P4: stage A-half1(t+2) | MFMA mhi x nhi | counted vmcnt ----
    if (kt + 2 < NT) stageA(q, 1, kt + 2);
    __builtin_amdgcn_s_barrier();
    __builtin_amdgcn_s_setprio(1);
#pragma unroll
    for (int ks = 0; ks < 2; ++ks)
#pragma unroll
      for (int m = 4; m < 8; ++m)
#pragma unroll
        for (int n = 2; n < 4; ++n)
          acc[m][n] = __builtin_amdgcn_mfma_f32_16x16x32_bf16(
              af[m][ks], bf[n][ks], acc[m][n], 0, 0, 0);
    __builtin_amdgcn_s_setprio(0);
    if (kt + 2 < NT) {
      asm volatile("s_waitcnt vmcnt(4)" ::: "memory");
    } else {
      asm volatile("s_waitcnt vmcnt(0)" ::: "memory");
    }
    __builtin_amdgcn_sched_barrier(0);
    __builtin_amdgcn_s_barrier();
  }

  // ---- epilogue ----
#pragma unroll
  for (int mi = 0; mi < 8; ++mi) {
    int grow0 = brow + wm * 128 + mi * 16 + l4 * 4;
#pragma unroll
    for (int n = 0; n < 4; ++n) {
      int gcol = bcol + wn * 64 + n * 16 + l15;
#pragma unroll
      for (int r = 0; r < 4; ++r) {
        float v = acc[mi][n][r];
        if (MODE == 1) {
          Cf[(size_t)(grow0 + r) * N + gcol] = v;
        } else {  // MODE 3 — 256-wide block stays within one output region
          if (bcol < 2048)
            Cb[(size_t)(grow0 + r) * 2048 + gcol] = f2bf(v * QSCALE);
          else if (bcol < 2560)
            Cb2[(size_t)(grow0 + r) * 512 + (gcol - 2048)] = f2bf(v);
          else
            Cb3[(size_t)(grow0 + r) * 512 + (gcol - 2560)] = f2bf(v);
        }
      }
    }
  }
}

// ---------------- GEMM 128x128 (wo projection): BK=64, T2 swizzle -------------
template <int MODE>
__global__ __launch_bounds__(256) void gemm_bt(
    const u16* __restrict__ A, const u16* __restrict__ BT,
    float* __restrict__ Cf, u16* __restrict__ Cb, u16* __restrict__ Cb2,
    u16* __restrict__ Cb3, int M, int N) {
  constexpr int K = 2048;
  __shared__ __align__(16) u16 As[128 * 64];
  __shared__ __align__(16) u16 Bs[128 * 64];
  const int t = threadIdx.x;
  const int lane = t & 63;
  const int w = t >> 6;
  const int wr = w >> 1, wc = w & 1;
  const int l15 = lane & 15;
  const int l4 = lane >> 4;

  const int nwg = gridDim.x * gridDim.y;
  const int bid = blockIdx.y * gridDim.x + blockIdx.x;
  const int wg = (bid & 7) * (nwg >> 3) + (bid >> 3);
  const int brow = (wg / gridDim.x) * 128;
  const int bcol = (wg % gridDim.x) * 128;

  f32x4 acc[4][4];
#pragma unroll
  for (int m = 0; m < 4; m++)
#pragma unroll
    for (int n = 0; n < 4; n++)
#pragma unroll
      for (int r = 0; r < 4; r++) acc[m][n][r] = 0.f;

  const int r0 = t >> 3;
  const int gcs = ((t & 7) ^ (r0 & 7)) * 8;
  const u16* pa = A + (size_t)(brow + r0) * K + gcs;
  const u16* pb = BT + (size_t)(bcol + r0) * K + gcs;
  u16* const la = &As[t * 8];
  u16* const lb = &Bs[t * 8];

  for (int kk = 0; kk < K; kk += 64) {
#pragma unroll
    for (int c = 0; c < 4; ++c) {
      gload_lds16(pa + (size_t)c * 32 * K, la + c * 2048);
      gload_lds16(pb + (size_t)c * 32 * K, lb + c * 2048);
    }
    pa += 64;
    pb += 64;
    __syncthreads();
#pragma unroll
    for (int ks2 = 0; ks2 < 2; ++ks2) {
      bf16x8 a[4], b[4];
#pragma unroll
      for (int m = 0; m < 4; m++) {
        int row = wr * 64 + m * 16 + l15;
        a[m] = *reinterpret_cast<const bf16x8*>(
            &As[row * 64 + (((ks2 * 4 + l4) ^ (row & 7)) * 8)]);
      }
#pragma unroll
      for (int n = 0; n < 4; n++) {
        int row = wc * 64 + n * 16 + l15;
        b[n] = *reinterpret_cast<const bf16x8*>(
            &Bs[row * 64 + (((ks2 * 4 + l4) ^ (row & 7)) * 8)]);
      }
#pragma unroll
      for (int m = 0; m < 4; m++)
#pragma unroll
        for (int n = 0; n < 4; n++)
          acc[m][n] = __builtin_amdgcn_mfma_f32_16x16x32_bf16(a[m], b[n], acc[m][n], 0, 0, 0);
    }
    __syncthreads();
  }

#pragma unroll
  for (int m = 0; m < 4; m++) {
    int grow0 = brow + wr * 64 + m * 16 + l4 * 4;
#pragma unroll
    for (int n = 0; n < 4; n++) {
      int gcol = bcol + wc * 64 + n * 16 + l15;
#pragma unroll
      for (int r = 0; r < 4; r++) {
        if (MODE == 1) {
          Cf[(size_t)(grow0 + r) * N + gcol] = acc[m][n][r];
        } else {
          if (bcol < 2048)
            Cb[(size_t)(grow0 + r) * 2048 + gcol] = f2bf(acc[m][n][r] * QSCALE);
          else if (bcol < 2560)
            Cb2[(size_t)(grow0 + r) * 512 + (gcol - 2048)] = f2bf(acc[m][n][r]);
          else
            Cb3[(size_t)(grow0 + r) * 512 + (gcol - 2560)] = f2bf(acc[m][n][r]);
        }
      }
    }
  }
}

// ---------------- flash attention v6 (causal, GQA, swapped QK^T) ----------------
// QBLK=64, grid (16,32,2)=1024 blocks, 4 waves of 16 q-rows, LDS 40KB ->
// 4 blocks/CU = 16 waves/CU. Block jj: q-tile (31-jj) then jj -> 33 steps.
__global__ __launch_bounds__(256, 4) void attn_kernel(
    const u16* __restrict__ Qb, const u16* __restrict__ Kb,
    const u16* __restrict__ VT, u16* __restrict__ Ob) {
  const int jj = blockIdx.x;  // 0..15
  const int h = blockIdx.y, b = blockIdx.z;
  const int kvh = h >> 2;
  const int t = threadIdx.x;
  const int lane = t & 63;
  const int w = t >> 6;
  const int q15 = lane & 15, g = lane >> 4;

  __shared__ __align__(16) u16 Ks[2][64 * 64];
  __shared__ __align__(16) u16 Vs[2][64 * 64];  // V^T tile: [d][kv]
  __shared__ __align__(16) u32 Pu[4][16 * 32];  // per-wave P / epilogue buffer

  const size_t Krow0 = (size_t)b * 2048;
  const size_t Vrow0 = ((size_t)b * 8 + kvh) * 64;

  auto stage = [&](int buf, int kvbase) {
#pragma unroll
    for (int c = 0; c < 2; ++c) {
      int chunk = c * 256 + t;
      int row = chunk >> 3, gg = chunk & 7;
      int gcs = (gg ^ (row & 7)) * 8;
      gload_lds16(&Kb[(Krow0 + kvbase + row) * 512 + kvh * 64 + gcs],
                  &Ks[buf][chunk * 8]);
      gload_lds16(&VT[(Vrow0 + row) * 2048 + kvbase + gcs],
                  &Vs[buf][chunk * 8]);
    }
  };

  const int swzB = (q15 & 7) << 3;
  const int swzP = (q15 & 7) << 2;
  u32* const pw = &Pu[w][0];
  const int nA = 32 - jj;
  const int nsteps = 33;
  auto kvb_of = [&](int ss) { return ((ss < nA) ? ss : ss - nA) << 6; };

  stage(0, 0);
  __syncthreads();
  int cur = 0;
  int ss = 0;

#pragma unroll
  for (int ph = 0; ph < 2; ++ph) {
    const int qt = ph ? jj : 31 - jj;
    const int nkv = qt + 1;
    const int wq0 = qt * 64 + w * 16;

    bf16x8 qf[2];
    {
      const u16* q0 = &Qb[((size_t)b * 2048 + wq0 + q15) * 2048 + h * 64 + g * 8];
      qf[0] = *reinterpret_cast<const bf16x8*>(q0);
      qf[1] = *reinterpret_cast<const bf16x8*>(q0 + 32);
    }

    f32x4 oo[4];
#pragma unroll
    for (int c = 0; c < 4; c++)
#pragma unroll
      for (int r = 0; r < 4; r++) oo[c][r] = 0.f;
    float mr = -1e30f, lr = 0.f;

    for (int kv = 0; kv < nkv; ++kv, ++ss) {
      const int kvbase = kv << 6;
      if (ss + 1 < nsteps) stage(cur ^ 1, kvb_of(ss + 1));

      f32x4 s[4];
#pragma unroll
      for (int c = 0; c < 4; c++)
#pragma unroll
        for (int r = 0; r < 4; r++) s[c][r] = 0.f;
      __builtin_amdgcn_s_setprio(1);
#pragma unroll
      for (int ks = 0; ks < 2; ++ks) {
        const int kcol = (ks * 32 + g * 8) ^ swzB;
#pragma unroll
        for (int c = 0; c < 4; c++) {
          bf16x8 kb = *reinterpret_cast<const bf16x8*>(
              &Ks[cur][(c * 16 + q15) * 64 + kcol]);
          s[c] = __builtin_amdgcn_mfma_f32_16x16x32_bf16(kb, qf[ks], s[c], 0, 0, 0);
        }
      }
      __builtin_amdgcn_s_setprio(0);

      if (kv == qt) {
        const int qg = wq0 + q15;
#pragma unroll
        for (int c = 0; c < 4; c++)
#pragma unroll
          for (int r = 0; r < 4; r++)
            if (kvbase + c * 16 + g * 4 + r > qg) s[c][r] = -1e30f;
      }

      float mx0 = fmaxf(fmaxf(s[0][0], s[0][1]), fmaxf(s[0][2], s[0][3]));
      float mx1 = fmaxf(fmaxf(s[1][0], s[1][1]), fmaxf(s[1][2], s[1][3]));
      float mx2 = fmaxf(fmaxf(s[2][0], s[2][1]), fmaxf(s[2][2], s[2][3]));
      float mx3 = fmaxf(fmaxf(s[3][0], s[3][1]), fmaxf(s[3][2], s[3][3]));
      float mx = fmaxf(fmaxf(mx0, mx1), fmaxf(mx2, mx3));
      mx = fmaxf(mx, __shfl_xor(mx, 16));
      mx = fmaxf(mx, __shfl_xor(mx, 32));
      if (!__all(mx <= mr + 8.f)) {
        float mnew = fmaxf(mr, mx);
        float alpha = fexp2(mr - mnew);
        lr *= alpha;
#pragma unroll
        for (int c = 0; c < 4; c++)
#pragma unroll
          for (int r = 0; r < 4; r++) oo[c][r] *= alpha;
        mr = mnew;
      }
      float p[4][4];
      float rs = 0.f;
#pragma unroll
      for (int c = 0; c < 4; c++) {
        float t0 = fexp2(s[c][0] - mr);
        float t1 = fexp2(s[c][1] - mr);
        float t2 = fexp2(s[c][2] - mr);
        float t3 = fexp2(s[c][3] - mr);
        p[c][0] = t0; p[c][1] = t1; p[c][2] = t2; p[c][3] = t3;
        rs += (t0 + t1) + (t2 + t3);
      }
      rs += __shfl_xor(rs, 16);
      rs += __shfl_xor(rs, 32);
      lr += rs;
#pragma unroll
      for (int c = 0; c < 4; c++) {
        u64 wv = (u64)packbf2(p[c][0], p[c][1]) |
                 ((u64)packbf2(p[c][2], p[c][3]) << 32);
        *reinterpret_cast<u64*>(&pw[q15 * 32 + ((c * 8 + g * 2) ^ swzP)]) = wv;
      }
      bf16x8 pb[2];
#pragma unroll
      for (int ks = 0; ks < 2; ++ks)
        pb[ks] = *reinterpret_cast<const bf16x8*>(
            &pw[q15 * 32 + ((ks * 16 + g * 4) ^ swzP)]);

      __builtin_amdgcn_s_setprio(1);
#pragma unroll
      for (int ks = 0; ks < 2; ++ks) {
        const int vcol = (ks * 32 + g * 8) ^ swzB;
#pragma unroll
        for (int c2 = 0; c2 < 4; c2++) {
          bf16x8 vb = *reinterpret_cast<const bf16x8*>(
              &Vs[cur][(c2 * 16 + q15) * 64 + vcol]);
          oo[c2] = __builtin_amdgcn_mfma_f32_16x16x32_bf16(vb, pb[ks], oo[c2], 0, 0, 0);
        }
      }
      __builtin_amdgcn_s_setprio(0);

      __syncthreads();
      cur ^= 1;
    }

    const int qq = lane >> 2, cl = lane & 3;
    const int swq = (qq & 7) << 2;
    {
      float rcp = 1.0f / lr;
#pragma unroll
      for (int c2 = 0; c2 < 4; c2++) {
        u64 wv = (u64)packbf2(oo[c2][0] * rcp, oo[c2][1] * rcp) |
                 ((u64)packbf2(oo[c2][2] * rcp, oo[c2][3] * rcp) << 32);
        *reinterpret_cast<u64*>(&pw[q15 * 32 + ((c2 * 8 + g * 2) ^ swzP)]) = wv;
      }
      uint4 d0 = *reinterpret_cast<const uint4*>(&pw[qq * 32 + ((cl * 4) ^ swq)]);
      uint4 d1 = *reinterpret_cast<const uint4*>(&pw[qq * 32 + ((cl * 4 + 16) ^ swq)]);
      u32* og = (u32*)Ob + ((size_t)b * 2048 + wq0 + qq) * 1024 + h * 32;
      *reinterpret_cast<uint4*>(&og[cl * 4]) = d0;
      *reinterpret_cast<uint4*>(&og[cl * 4 + 16]) = d1;
    }
  }
}

// ---------------- launcher ----------------
extern "C" void kernel_launch(void* const* d_in, const int* in_sizes, int n_in,
                              void* d_out, int out_size, void* d_ws, size_t ws_size,
                              hipStream_t stream) {
  const float* x = (const float*)d_in[0];
  const float* wq = (const float*)d_in[1];
  const float* wk = (const float*)d_in[2];
  const float* wv = (const float*)d_in[3];
  const float* wo = (const float*)d_in[4];
  float* out = (float*)d_out;

  char* p = (char*)d_ws;
  u16* xb = (u16*)p;   p += (size_t)4096 * 2048 * 2;
  u16* wqT = (u16*)p;  p += (size_t)2048 * 2048 * 2;  // wqT|wkT|wvT contiguous
  u16* wkT = (u16*)p;  p += (size_t)512 * 2048 * 2;
  u16* wvT = (u16*)p;  p += (size_t)512 * 2048 * 2;
  u16* woT = (u16*)p;  p += (size_t)2048 * 2048 * 2;
  u16* Qb = (u16*)p;   p += (size_t)4096 * 2048 * 2;
  u16* Kb = (u16*)p;   p += (size_t)4096 * 512 * 2;
  u16* Vb = (u16*)p;   p += (size_t)4096 * 512 * 2;
  u16* VTb = (u16*)p;  p += (size_t)2 * 512 * 2048 * 2;
  u16* attn = xb;  // reuse: x_bf16 dead after projections

  cast_f32_bf16<<<8192, 256, 0, stream>>>(x, xb, 4096 * 2048);
  transpose_cast_all<<<dim3(64, 64, 4), 256, 0, stream>>>(
      wq, wk, wv, wo, wqT, wkT, wvT, woT);

  // fused Q|K|V projection — 256^2 tile, 4-phase counted-vmcnt pipeline
  gemm256<3><<<dim3(3072 / 256, 4096 / 256), 512, 0, stream>>>(
      xb, wqT, nullptr, Qb, Kb, Vb, 4096, 3072);

  transpose_u16<<<dim3(2048 / 32, 512 / 32, 2), 256, 0, stream>>>(Vb, VTb);

  attn_kernel<<<dim3(16, 32, 2), 256, 0, stream>>>(Qb, Kb, VTb, attn);

  gemm_bt<1><<<dim3(2048 / 128, 4096 / 128), 256, 0, stream>>>(
      attn, woT, out, nullptr, nullptr, nullptr, 4096, 2048);
}

// Round 10
// 193.858 us; speedup vs baseline: 1.3545x; 1.0249x over previous
//
#include <hip/hip_runtime.h>

typedef unsigned short u16;
typedef unsigned int u32;
typedef unsigned long long u64;

typedef __bf16 bf16x8 __attribute__((ext_vector_type(8)));
typedef float f32x4 __attribute__((ext_vector_type(4)));
typedef u16 u16x4 __attribute__((ext_vector_type(4)));

__device__ __forceinline__ u16 f2bf(float f) {
  u32 u = __builtin_bit_cast(u32, f);
  u += 0x7fffu + ((u >> 16) & 1u);
  return (u16)(u >> 16);
}

__device__ __forceinline__ u32 packbf2(float a, float b) {
  __bf16 x = (__bf16)a, y = (__bf16)b;
  return (u32)__builtin_bit_cast(u16, x) | ((u32)__builtin_bit_cast(u16, y) << 16);
}

__device__ __forceinline__ float fexp2(float x) {
#if __has_builtin(__builtin_amdgcn_exp2f)
  return __builtin_amdgcn_exp2f(x);
#else
  return exp2f(x);
#endif
}

__device__ __forceinline__ void gload_lds16(const void* g, void* lds) {
  __builtin_amdgcn_global_load_lds(
      (const __attribute__((address_space(1))) void*)g,
      (__attribute__((address_space(3))) void*)lds, 16, 0, 0);
}

// 0.125 (1/sqrt(64)) * log2(e) — folded into Q projection so softmax runs in exp2 domain
#define QSCALE 0.18033688011112043f

// ---------------- cast x: fp32 -> bf16 ----------------
__global__ __launch_bounds__(256) void cast_f32_bf16(
    const float* __restrict__ in, u16* __restrict__ out, int n4) {
  int i = (blockIdx.x * 256 + threadIdx.x) * 4;
  float4 v = *reinterpret_cast<const float4*>(in + i);
  u16x4 o;
  o[0] = f2bf(v.x); o[1] = f2bf(v.y); o[2] = f2bf(v.z); o[3] = f2bf(v.w);
  *reinterpret_cast<u16x4*>(out + i) = o;
}

// ---------------- fused transpose+cast for all 4 weights (K=2048 rows) --------
__global__ __launch_bounds__(256) void transpose_cast_all(
    const float* __restrict__ wq, const float* __restrict__ wk,
    const float* __restrict__ wv, const float* __restrict__ wo,
    u16* __restrict__ wqT, u16* __restrict__ wkT,
    u16* __restrict__ wvT, u16* __restrict__ woT) {
  constexpr int K = 2048;
  const float* w_;
  u16* wt;
  int N;
  switch (blockIdx.z) {
    case 0: w_ = wq; wt = wqT; N = 2048; break;
    case 1: w_ = wo; wt = woT; N = 2048; break;
    case 2: w_ = wk; wt = wkT; N = 512; break;
    default: w_ = wv; wt = wvT; N = 512; break;
  }
  int bx = blockIdx.x * 32;  // n
  if (bx >= N) return;
  int by = blockIdx.y * 32;  // k
  __shared__ float tile[32][33];
  int tx = threadIdx.x & 31, ty = threadIdx.x >> 5;
#pragma unroll
  for (int i = 0; i < 32; i += 8)
    tile[ty + i][tx] = w_[(size_t)(by + ty + i) * N + bx + tx];
  __syncthreads();
#pragma unroll
  for (int i = 0; i < 32; i += 8)
    wt[(size_t)(bx + ty + i) * K + by + tx] = f2bf(tile[tx][ty + i]);
}

// ---------------- GEMM 256x256 QKV, BK=64, 8 waves, 4-phase counted-vmcnt ------
// (R9-verified schedule.) MODE 3 split: cols [0,2048)->Q (ld2048, xQSCALE),
// [2048,2560)->K (ld512), [2560,3072)->V written DIRECTLY TRANSPOSED into
// VT[(b*512+col)][t] (u64 pack of 4 consecutive t-rows) — replaces transpose_u16.
template <int MODE>
__global__ __launch_bounds__(512, 2) void gemm256(
    const u16* __restrict__ A, const u16* __restrict__ BT,
    float* __restrict__ Cf, u16* __restrict__ Cb, u16* __restrict__ Cb2,
    u16* __restrict__ Cb3, int M, int N) {
  constexpr int K = 2048, NT = 32;
  __shared__ __align__(16) u16 Ab[2][256 * 64];
  __shared__ __align__(16) u16 Bb[2][256 * 64];
  const int t = threadIdx.x;
  const int lane = t & 63;
  const int w = t >> 6;
  const int wm = w >> 2, wn = w & 3;  // 2M x 4N waves; per-wave out 128x64
  const int l15 = lane & 15, l4 = lane >> 4;

  const int nwg = gridDim.x * gridDim.y;
  const int bid = blockIdx.y * gridDim.x + blockIdx.x;
  const int wg = (bid & 7) * (nwg >> 3) + (bid >> 3);
  const int brow = (wg / gridDim.x) * 256;
  const int bcol = (wg % gridDim.x) * 256;

  const int r0 = t >> 3;
  const int gc = ((t & 7) ^ (r0 & 7)) * 8;
  auto stageA = [&](int q, int h, int kt) {
    const u16* src = A + (size_t)(brow + h * 128 + r0) * K + kt * 64 + gc;
    u16* dst = &Ab[q][(h * 128 + r0) * 64 + (t & 7) * 8];
    gload_lds16(src, dst);
    gload_lds16(src + (size_t)64 * K, dst + 64 * 64);
  };
  auto stageB = [&](int q, int h, int kt) {
    const u16* src = BT + (size_t)(bcol + h * 128 + r0) * K + kt * 64 + gc;
    u16* dst = &Bb[q][(h * 128 + r0) * 64 + (t & 7) * 8];
    gload_lds16(src, dst);
    gload_lds16(src + (size_t)64 * K, dst + 64 * 64);
  };

  f32x4 acc[8][4];
#pragma unroll
  for (int mi = 0; mi < 8; mi++)
#pragma unroll
    for (int n = 0; n < 4; n++)
#pragma unroll
      for (int r = 0; r < 4; r++) acc[mi][n][r] = 0.f;

  stageA(0, 0, 0); stageA(0, 1, 0);
  stageB(0, 0, 0); stageB(0, 1, 0);
  stageA(1, 0, 1); stageA(1, 1, 1);
  asm volatile("s_waitcnt vmcnt(4)" ::: "memory");
  __builtin_amdgcn_sched_barrier(0);
  __builtin_amdgcn_s_barrier();

  for (int kt = 0; kt < NT; ++kt) {
    const int q = kt & 1;
    const u16* Al = Ab[q];
    const u16* Bl = Bb[q];
    bf16x8 af[8][2], bf[4][2];

    // P1
#pragma unroll
    for (int m = 0; m < 4; ++m) {
      int row = wm * 128 + m * 16 + l15;
#pragma unroll
      for (int ks = 0; ks < 2; ++ks)
        af[m][ks] = *reinterpret_cast<const bf16x8*>(
            &Al[row * 64 + (((ks * 4 + l4) ^ (row & 7)) * 8)]);
    }
#pragma unroll
    for (int n = 0; n < 2; ++n) {
      int row = wn * 64 + n * 16 + l15;
#pragma unroll
      for (int ks = 0; ks < 2; ++ks)
        bf[n][ks] = *reinterpret_cast<const bf16x8*>(
            &Bl[row * 64 + (((ks * 4 + l4) ^ (row & 7)) * 8)]);
    }
    if (kt + 1 < NT) stageB(q ^ 1, 0, kt + 1);
    __builtin_amdgcn_s_barrier();
    __builtin_amdgcn_s_setprio(1);
#pragma unroll
    for (int ks = 0; ks < 2; ++ks)
#pragma unroll
      for (int m = 0; m < 4; ++m)
#pragma unroll
        for (int n = 0; n < 2; ++n)
          acc[m][n] = __builtin_amdgcn_mfma_f32_16x16x32_bf16(
              af[m][ks], bf[n][ks], acc[m][n], 0, 0, 0);
    __builtin_amdgcn_s_setprio(0);
    __builtin_amdgcn_s_barrier();

    // P2
#pragma unroll
    for (int m = 4; m < 8; ++m) {
      int row = wm * 128 + m * 16 + l15;
#pragma unroll
      for (int ks = 0; ks < 2; ++ks)
        af[m][ks] = *reinterpret_cast<const bf16x8*>(
            &Al[row * 64 + (((ks * 4 + l4) ^ (row & 7)) * 8)]);
    }
#pragma unroll
    for (int n = 2; n < 4; ++n) {
      int row = wn * 64 + n * 16 + l15;
#pragma unroll
      for (int ks = 0; ks < 2; ++ks)
        bf[n][ks] = *reinterpret_cast<const bf16x8*>(
            &Bl[row * 64 + (((ks * 4 + l4) ^ (row & 7)) * 8)]);
    }
    if (kt + 1 < NT) stageB(q ^ 1, 1, kt + 1);
    __builtin_amdgcn_s_barrier();
    __builtin_amdgcn_s_setprio(1);
#pragma unroll
    for (int ks = 0; ks < 2; ++ks)
#pragma unroll
      for (int m = 0; m < 4; ++m)
#pragma unroll
        for (int n = 2; n < 4; ++n)
          acc[m][n] = __builtin_amdgcn_mfma_f32_16x16x32_bf16(
              af[m][ks], bf[n][ks], acc[m][n], 0, 0, 0);
    __builtin_amdgcn_s_setprio(0);
    __builtin_amdgcn_s_barrier();

    // P3
    if (kt + 2 < NT) stageA(q, 0, kt + 2);
    __builtin_amdgcn_s_barrier();
    __builtin_amdgcn_s_setprio(1);
#pragma unroll
    for (int ks = 0; ks < 2; ++ks)
#pragma unroll
      for (int m = 4; m < 8; ++m)
#pragma unroll
        for (int n = 0; n < 2; ++n)
          acc[m][n] = __builtin_amdgcn_mfma_f32_16x16x32_bf16(
              af[m][ks], bf[n][ks], acc[m][n], 0, 0, 0);
    __builtin_amdgcn_s_setprio(0);
    __builtin_amdgcn_s_barrier();

    // P4
    if (kt + 2 < NT) stageA(q, 1, kt + 2);
    __builtin_amdgcn_s_barrier();
    __builtin_amdgcn_s_setprio(1);
#pragma unroll
    for (int ks = 0; ks < 2; ++ks)
#pragma unroll
      for (int m = 4; m < 8; ++m)
#pragma unroll
        for (int n = 2; n < 4; ++n)
          acc[m][n] = __builtin_amdgcn_mfma_f32_16x16x32_bf16(
              af[m][ks], bf[n][ks], acc[m][n], 0, 0, 0);
    __builtin_amdgcn_s_setprio(0);
    if (kt + 2 < NT) {
      asm volatile("s_waitcnt vmcnt(4)" ::: "memory");
    } else {
      asm volatile("s_waitcnt vmcnt(0)" ::: "memory");
    }
    __builtin_amdgcn_sched_barrier(0);
    __builtin_amdgcn_s_barrier();
  }

  // ---- epilogue ----
#pragma unroll
  for (int mi = 0; mi < 8; ++mi) {
    int grow0 = brow + wm * 128 + mi * 16 + l4 * 4;
#pragma unroll
    for (int n = 0; n < 4; ++n) {
      int gcol = bcol + wn * 64 + n * 16 + l15;
      if (MODE == 1) {
#pragma unroll
        for (int r = 0; r < 4; ++r)
          Cf[(size_t)(grow0 + r) * N + gcol] = acc[mi][n][r];
      } else if (bcol < 2048) {
#pragma unroll
        for (int r = 0; r < 4; ++r)
          Cb[(size_t)(grow0 + r) * 2048 + gcol] = f2bf(acc[mi][n][r] * QSCALE);
      } else if (bcol < 2560) {
#pragma unroll
        for (int r = 0; r < 4; ++r)
          Cb2[(size_t)(grow0 + r) * 512 + (gcol - 2048)] = f2bf(acc[mi][n][r]);
      } else {
        // V region: write directly transposed into VT[(b*512+col)][t]
        int col = gcol - 2560;
        int bb = grow0 >> 11, tt = grow0 & 2047;  // block never crosses b
        u64 wv = (u64)packbf2(acc[mi][n][0], acc[mi][n][1]) |
                 ((u64)packbf2(acc[mi][n][2], acc[mi][n][3]) << 32);
        *reinterpret_cast<u64*>(&Cb3[((size_t)(bb * 512 + col)) * 2048 + tt]) = wv;
      }
    }
  }
}

// ---------------- GEMM 256x128 (wo), BK=64, 8 waves, 4-phase counted-vmcnt -----
// Same schedule skeleton as gemm256 (R9-verified), geometry rescaled for 100%
// grid fill at M=4096,N=2048 (grid 16x16=256 blocks). Waves 4M x 2N, per-wave
// 64x64 out. Stage halves: A=128 rows (2 loads/thread), B=64 rows (1 load).
// End-of-tile in-flight = A(t+2) = 4 loads -> vmcnt(4).
__global__ __launch_bounds__(512, 2) void gemm256n(
    const u16* __restrict__ A, const u16* __restrict__ BT,
    float* __restrict__ Cf, int M, int N) {
  constexpr int K = 2048, NT = 32;
  __shared__ __align__(16) u16 Ab[2][256 * 64];
  __shared__ __align__(16) u16 Bb[2][128 * 64];
  const int t = threadIdx.x;
  const int lane = t & 63;
  const int w = t >> 6;
  const int wm = w >> 1, wn = w & 1;  // 4M x 2N
  const int l15 = lane & 15, l4 = lane >> 4;

  const int nwg = gridDim.x * gridDim.y;
  const int bid = blockIdx.y * gridDim.x + blockIdx.x;
  const int wg = (bid & 7) * (nwg >> 3) + (bid >> 3);
  const int brow = (wg / gridDim.x) * 256;
  const int bcol = (wg % gridDim.x) * 128;

  const int r0 = t >> 3;
  const int gc = ((t & 7) ^ (r0 & 7)) * 8;
  auto stageA = [&](int q, int h, int kt) {
    const u16* src = A + (size_t)(brow + h * 128 + r0) * K + kt * 64 + gc;
    u16* dst = &Ab[q][(h * 128 + r0) * 64 + (t & 7) * 8];
    gload_lds16(src, dst);
    gload_lds16(src + (size_t)64 * K, dst + 64 * 64);
  };
  auto stageB = [&](int q, int h, int kt) {  // half = 64 rows, 1 load/thread
    const u16* src = BT + (size_t)(bcol + h * 64 + r0) * K + kt * 64 + gc;
    u16* dst = &Bb[q][(h * 64 + r0) * 64 + (t & 7) * 8];
    gload_lds16(src, dst);
  };

  f32x4 acc[4][4];
#pragma unroll
  for (int m = 0; m < 4; m++)
#pragma unroll
    for (int n = 0; n < 4; n++)
#pragma unroll
      for (int r = 0; r < 4; r++) acc[m][n][r] = 0.f;

  stageA(0, 0, 0); stageA(0, 1, 0);
  stageB(0, 0, 0); stageB(0, 1, 0);
  stageA(1, 0, 1); stageA(1, 1, 1);
  asm volatile("s_waitcnt vmcnt(4)" ::: "memory");
  __builtin_amdgcn_sched_barrier(0);
  __builtin_amdgcn_s_barrier();

  for (int kt = 0; kt < NT; ++kt) {
    const int q = kt & 1;
    const u16* Al = Ab[q];
    const u16* Bl = Bb[q];
    bf16x8 af[4][2], bf[4][2];

    // P1: read A m0-1 + B n0-1 | stage B-h0(t+1) | MFMA m01 x n01
#pragma unroll
    for (int m = 0; m < 2; ++m) {
      int row = wm * 64 + m * 16 + l15;
#pragma unroll
      for (int ks = 0; ks < 2; ++ks)
        af[m][ks] = *reinterpret_cast<const bf16x8*>(
            &Al[row * 64 + (((ks * 4 + l4) ^ (row & 7)) * 8)]);
    }
#pragma unroll
    for (int n = 0; n < 2; ++n) {
      int row = wn * 64 + n * 16 + l15;
#pragma unroll
      for (int ks = 0; ks < 2; ++ks)
        bf[n][ks] = *reinterpret_cast<const bf16x8*>(
            &Bl[row * 64 + (((ks * 4 + l4) ^ (row & 7)) * 8)]);
    }
    if (kt + 1 < NT) stageB(q ^ 1, 0, kt + 1);
    __builtin_amdgcn_s_barrier();
    __builtin_amdgcn_s_setprio(1);
#pragma unroll
    for (int ks = 0; ks < 2; ++ks)
#pragma unroll
      for (int m = 0; m < 2; ++m)
#pragma unroll
        for (int n = 0; n < 2; ++n)
          acc[m][n] = __builtin_amdgcn_mfma_f32_16x16x32_bf16(
              af[m][ks], bf[n][ks], acc[m][n], 0, 0, 0);
    __builtin_amdgcn_s_setprio(0);
    __builtin_amdgcn_s_barrier();

    // P2: read A m2-3 + B n2-3 | stage B-h1(t+1) | MFMA m01 x n23
#pragma unroll
    for (int m = 2; m < 4; ++m) {
      int row = wm * 64 + m * 16 + l15;
#pragma unroll
      for (int ks = 0; ks < 2; ++ks)
        af[m][ks] = *reinterpret_cast<const bf16x8*>(
            &Al[row * 64 + (((ks * 4 + l4) ^ (row & 7)) * 8)]);
    }
#pragma unroll
    for (int n = 2; n < 4; ++n) {
      int row = wn * 64 + n * 16 + l15;
#pragma unroll
      for (int ks = 0; ks < 2; ++ks)
        bf[n][ks] = *reinterpret_cast<const bf16x8*>(
            &Bl[row * 64 + (((ks * 4 + l4) ^ (row & 7)) * 8)]);
    }
    if (kt + 1 < NT) stageB(q ^ 1, 1, kt + 1);
    __builtin_amdgcn_s_barrier();
    __builtin_amdgcn_s_setprio(1);
#pragma unroll
    for (int ks = 0; ks < 2; ++ks)
#pragma unroll
      for (int m = 0; m < 2; ++m)
#pragma unroll
        for (int n = 2; n < 4; ++n)
          acc[m][n] = __builtin_amdgcn_mfma_f32_16x16x32_bf16(
              af[m][ks], bf[n][ks], acc[m][n], 0, 0, 0);
    __builtin_amdgcn_s_setprio(0);
    __builtin_amdgcn_s_barrier();

    // P3: stage A-h0(t+2) | MFMA m23 x n01
    if (kt + 2 < NT) stageA(q, 0, kt + 2);
    __builtin_amdgcn_s_barrier();
    __builtin_amdgcn_s_setprio(1);
#pragma unroll
    for (int ks = 0; ks < 2; ++ks)
#pragma unroll
      for (int m = 2; m < 4; ++m)
#pragma unroll
        for (int n = 0; n < 2; ++n)
          acc[m][n] = __builtin_amdgcn_mfma_f32_16x16x32_bf16(
              af[m][ks], bf[n][ks], acc[m][n], 0, 0, 0);
    __builtin_amdgcn_s_setprio(0);
    __builtin_amdgcn_s_barrier();

    // P4: stage A-h1(t+2) | MFMA m23 x n23 | counted vmcnt
    if (kt + 2 < NT) stageA(q, 1, kt + 2);
    __builtin_amdgcn_s_barrier();
    __builtin_amdgcn_s_setprio(1);
#pragma unroll
    for (int ks = 0; ks < 2; ++ks)
#pragma unroll
      for (int m = 2; m < 4; ++m)
#pragma unroll
        for (int n = 2; n < 4; ++n)
          acc[m][n] = __builtin_amdgcn_mfma_f32_16x16x32_bf16(
              af[m][ks], bf[n][ks], acc[m][n], 0, 0, 0);
    __builtin_amdgcn_s_setprio(0);
    if (kt + 2 < NT) {
      asm volatile("s_waitcnt vmcnt(4)" ::: "memory");
    } else {
      asm volatile("s_waitcnt vmcnt(0)" ::: "memory");
    }
    __builtin_amdgcn_sched_barrier(0);
    __builtin_amdgcn_s_barrier();
  }

#pragma unroll
  for (int m = 0; m < 4; ++m) {
    int grow0 = brow + wm * 64 + m * 16 + l4 * 4;
#pragma unroll
    for (int n = 0; n < 4; ++n) {
      int gcol = bcol + wn * 64 + n * 16 + l15;
#pragma unroll
      for (int r = 0; r < 4; ++r)
        Cf[(size_t)(grow0 + r) * N + gcol] = acc[m][n][r];
    }
  }
}

// ---------------- flash attention v7 (causal, GQA, swapped QK^T) ----------------
// QBLK=64, grid (16,32,2)=1024 blocks, 4 waves of 16 q-rows, LDS 40KB ->
// 4 blocks/CU. Block jj: q-tile (31-jj) then jj -> 33 steps. Staging addresses
// maintained as running pointers (v7: kills per-step 64-bit mad address chains).
__global__ __launch_bounds__(256, 4) void attn_kernel(
    const u16* __restrict__ Qb, const u16* __restrict__ Kb,
    const u16* __restrict__ VT, u16* __restrict__ Ob) {
  const int jj = blockIdx.x;  // 0..15
  const int h = blockIdx.y, b = blockIdx.z;
  const int kvh = h >> 2;
  const int t = threadIdx.x;
  const int lane = t & 63;
  const int w = t >> 6;
  const int q15 = lane & 15, g = lane >> 4;

  __shared__ __align__(16) u16 Ks[2][64 * 64];
  __shared__ __align__(16) u16 Vs[2][64 * 64];  // V^T tile: [d][kv]
  __shared__ __align__(16) u32 Pu[4][16 * 32];  // per-wave P / epilogue buffer

  const size_t Krow0 = (size_t)b * 2048;
  const size_t Vrow0 = ((size_t)b * 8 + kvh) * 64;

  // staging: per-thread constant dst + running src pointers
  u16* const dk0 = &Ks[0][t * 8];
  u16* const dk1 = &Ks[1][t * 8];
  u16* const dv0 = &Vs[0][t * 8];
  u16* const dv1 = &Vs[1][t * 8];
  const int row0 = t >> 3;  // 0..31
  const int gcs = ((t & 7) ^ (row0 & 7)) * 8;
  const u16* const pk0 = Kb + (Krow0 + row0) * 512 + kvh * 64 + gcs;
  const u16* const pv0 = VT + (Vrow0 + row0) * 2048 + gcs;
  const u16* kp = pk0;
  const u16* vp = pv0;

  auto stage = [&](int buf, const u16* kpp, const u16* vpp) {
    u16* dk = buf ? dk1 : dk0;
    u16* dv = buf ? dv1 : dv0;
    gload_lds16(kpp, dk);
    gload_lds16(kpp + 32 * 512, dk + 2048);
    gload_lds16(vpp, dv);
    gload_lds16(vpp + 32 * 2048, dv + 2048);
  };

  const int swzB = (q15 & 7) << 3;
  const int swzP = (q15 & 7) << 2;
  u32* const pw = &Pu[w][0];
  const int nA = 32 - jj;
  const int nsteps = 33;

  stage(0, kp, vp);
  __syncthreads();
  int cur = 0;
  int ss = 0;

#pragma unroll
  for (int ph = 0; ph < 2; ++ph) {
    const int qt = ph ? jj : 31 - jj;
    const int nkv = qt + 1;
    const int wq0 = qt * 64 + w * 16;

    bf16x8 qf[2];
    {
      const u16* q0 = &Qb[((size_t)b * 2048 + wq0 + q15) * 2048 + h * 64 + g * 8];
      qf[0] = *reinterpret_cast<const bf16x8*>(q0);
      qf[1] = *reinterpret_cast<const bf16x8*>(q0 + 32);
    }

    f32x4 oo[4];
#pragma unroll
    for (int c = 0; c < 4; c++)
#pragma unroll
      for (int r = 0; r < 4; r++) oo[c][r] = 0.f;
    float mr = -1e30f, lr = 0.f;

    for (int kv = 0; kv < nkv; ++kv, ++ss) {
      const int kvbase = kv << 6;
      if (ss + 1 < nsteps) {
        if (ss + 1 == nA) {
          kp = pk0;
          vp = pv0;
        } else {
          kp += 64 * 512;
          vp += 64;
        }
        stage(cur ^ 1, kp, vp);
      }

      f32x4 s[4];
#pragma unroll
      for (int c = 0; c < 4; c++)
#pragma unroll
        for (int r = 0; r < 4; r++) s[c][r] = 0.f;
      __builtin_amdgcn_s_setprio(1);
#pragma unroll
      for (int ks = 0; ks < 2; ++ks) {
        const int kcol = (ks * 32 + g * 8) ^ swzB;
#pragma unroll
        for (int c = 0; c < 4; c++) {
          bf16x8 kb = *reinterpret_cast<const bf16x8*>(
              &Ks[cur][(c * 16 + q15) * 64 + kcol]);
          s[c] = __builtin_amdgcn_mfma_f32_16x16x32_bf16(kb, qf[ks], s[c], 0, 0, 0);
        }
      }
      __builtin_amdgcn_s_setprio(0);

      if (kv == qt) {
        const int qg = wq0 + q15;
#pragma unroll
        for (int c = 0; c < 4; c++)
#pragma unroll
          for (int r = 0; r < 4; r++)
            if (kvbase + c * 16 + g * 4 + r > qg) s[c][r] = -1e30f;
      }

      float mx0 = fmaxf(fmaxf(s[0][0], s[0][1]), fmaxf(s[0][2], s[0][3]));
      float mx1 = fmaxf(fmaxf(s[1][0], s[1][1]), fmaxf(s[1][2], s[1][3]));
      float mx2 = fmaxf(fmaxf(s[2][0], s[2][1]), fmaxf(s[2][2], s[2][3]));
      float mx3 = fmaxf(fmaxf(s[3][0], s[3][1]), fmaxf(s[3][2], s[3][3]));
      float mx = fmaxf(fmaxf(mx0, mx1), fmaxf(mx2, mx3));
      mx = fmaxf(mx, __shfl_xor(mx, 16));
      mx = fmaxf(mx, __shfl_xor(mx, 32));
      if (!__all(mx <= mr + 8.f)) {
        float mnew = fmaxf(mr, mx);
        float alpha = fexp2(mr - mnew);
        lr *= alpha;
#pragma unroll
        for (int c = 0; c < 4; c++)
#pragma unroll
          for (int r = 0; r < 4; r++) oo[c][r] *= alpha;
        mr = mnew;
      }
      float p[4][4];
      float rs = 0.f;
#pragma unroll
      for (int c = 0; c < 4; c++) {
        float t0 = fexp2(s[c][0] - mr);
        float t1 = fexp2(s[c][1] - mr);
        float t2 = fexp2(s[c][2] - mr);
        float t3 = fexp2(s[c][3] - mr);
        p[c][0] = t0; p[c][1] = t1; p[c][2] = t2; p[c][3] = t3;
        rs += (t0 + t1) + (t2 + t3);
      }
      rs += __shfl_xor(rs, 16);
      rs += __shfl_xor(rs, 32);
      lr += rs;
#pragma unroll
      for (int c = 0; c < 4; c++) {
        u64 wv = (u64)packbf2(p[c][0], p[c][1]) |
                 ((u64)packbf2(p[c][2], p[c][3]) << 32);
        *reinterpret_cast<u64*>(&pw[q15 * 32 + ((c * 8 + g * 2) ^ swzP)]) = wv;
      }
      bf16x8 pb[2];
#pragma unroll
      for (int ks = 0; ks < 2; ++ks)
        pb[ks] = *reinterpret_cast<const bf16x8*>(
            &pw[q15 * 32 + ((ks * 16 + g * 4) ^ swzP)]);

      __builtin_amdgcn_s_setprio(1);
#pragma unroll
      for (int ks = 0; ks < 2; ++ks) {
        const int vcol = (ks * 32 + g * 8) ^ swzB;
#pragma unroll
        for (int c2 = 0; c2 < 4; c2++) {
          bf16x8 vb = *reinterpret_cast<const bf16x8*>(
              &Vs[cur][(c2 * 16 + q15) * 64 + vcol]);
          oo[c2] = __builtin_amdgcn_mfma_f32_16x16x32_bf16(vb, pb[ks], oo[c2], 0, 0, 0);
        }
      }
      __builtin_amdgcn_s_setprio(0);

      __syncthreads();
      cur ^= 1;
    }

    const int qq = lane >> 2, cl = lane & 3;
    const int swq = (qq & 7) << 2;
    {
      float rcp = 1.0f / lr;
#pragma unroll
      for (int c2 = 0; c2 < 4; c2++) {
        u64 wv = (u64)packbf2(oo[c2][0] * rcp, oo[c2][1] * rcp) |
                 ((u64)packbf2(oo[c2][2] * rcp, oo[c2][3] * rcp) << 32);
        *reinterpret_cast<u64*>(&pw[q15 * 32 + ((c2 * 8 + g * 2) ^ swzP)]) = wv;
      }
      uint4 d0 = *reinterpret_cast<const uint4*>(&pw[qq * 32 + ((cl * 4) ^ swq)]);
      uint4 d1 = *reinterpret_cast<const uint4*>(&pw[qq * 32 + ((cl * 4 + 16) ^ swq)]);
      u32* og = (u32*)Ob + ((size_t)b * 2048 + wq0 + qq) * 1024 + h * 32;
      *reinterpret_cast<uint4*>(&og[cl * 4]) = d0;
      *reinterpret_cast<uint4*>(&og[cl * 4 + 16]) = d1;
    }
  }
}

// ---------------- launcher ----------------
extern "C" void kernel_launch(void* const* d_in, const int* in_sizes, int n_in,
                              void* d_out, int out_size, void* d_ws, size_t ws_size,
                              hipStream_t stream) {
  const float* x = (const float*)d_in[0];
  const float* wq = (const float*)d_in[1];
  const float* wk = (const float*)d_in[2];
  const float* wv = (const float*)d_in[3];
  const float* wo = (const float*)d_in[4];
  float* out = (float*)d_out;

  char* p = (char*)d_ws;
  u16* xb = (u16*)p;   p += (size_t)4096 * 2048 * 2;
  u16* wqT = (u16*)p;  p += (size_t)2048 * 2048 * 2;  // wqT|wkT|wvT contiguous
  u16* wkT = (u16*)p;  p += (size_t)512 * 2048 * 2;
  u16* wvT = (u16*)p;  p += (size_t)512 * 2048 * 2;
  u16* woT = (u16*)p;  p += (size_t)2048 * 2048 * 2;
  u16* Qb = (u16*)p;   p += (size_t)4096 * 2048 * 2;
  u16* Kb = (u16*)p;   p += (size_t)4096 * 512 * 2;
  u16* VTb = (u16*)p;  p += (size_t)2 * 512 * 2048 * 2;
  u16* attn = xb;  // reuse: x_bf16 dead after projections

  cast_f32_bf16<<<8192, 256, 0, stream>>>(x, xb, 4096 * 2048);
  transpose_cast_all<<<dim3(64, 64, 4), 256, 0, stream>>>(
      wq, wk, wv, wo, wqT, wkT, wvT, woT);

  // fused Q|K|V projection — V written directly transposed (no transpose_u16)
  gemm256<3><<<dim3(3072 / 256, 4096 / 256), 512, 0, stream>>>(
      xb, wqT, nullptr, Qb, Kb, VTb, 4096, 3072);

  attn_kernel<<<dim3(16, 32, 2), 256, 0, stream>>>(Qb, Kb, VTb, attn);

  // wo projection — 256x128-tile 4-phase pipeline, 256 blocks = full fill
  gemm256n<<<dim3(2048 / 128, 4096 / 256), 512, 0, stream>>>(
      attn, woT, out, 4096, 2048);
}

// Round 11
// 191.245 us; speedup vs baseline: 1.3730x; 1.0137x over previous
//
#include <hip/hip_runtime.h>

typedef unsigned short u16;
typedef unsigned int u32;
typedef unsigned long long u64;

typedef __bf16 bf16x8 __attribute__((ext_vector_type(8)));
typedef float f32x4 __attribute__((ext_vector_type(4)));
typedef u16 u16x4 __attribute__((ext_vector_type(4)));

__device__ __forceinline__ u16 f2bf(float f) {
  u32 u = __builtin_bit_cast(u32, f);
  u += 0x7fffu + ((u >> 16) & 1u);
  return (u16)(u >> 16);
}

__device__ __forceinline__ u32 packbf2(float a, float b) {
  __bf16 x = (__bf16)a, y = (__bf16)b;
  return (u32)__builtin_bit_cast(u16, x) | ((u32)__builtin_bit_cast(u16, y) << 16);
}

__device__ __forceinline__ float fexp2(float x) {
#if __has_builtin(__builtin_amdgcn_exp2f)
  return __builtin_amdgcn_exp2f(x);
#else
  return exp2f(x);
#endif
}

__device__ __forceinline__ void gload_lds16(const void* g, void* lds) {
  __builtin_amdgcn_global_load_lds(
      (const __attribute__((address_space(1))) void*)g,
      (__attribute__((address_space(3))) void*)lds, 16, 0, 0);
}

// 0.125 (1/sqrt(64)) * log2(e) — folded into Q projection so softmax runs in exp2 domain
#define QSCALE 0.18033688011112043f

// ---------------- fused prep: cast x (blocks 0..8191) + 4 weight transposes ----
__global__ __launch_bounds__(256) void prep_kernel(
    const float* __restrict__ x, u16* __restrict__ xb,
    const float* __restrict__ wq, const float* __restrict__ wk,
    const float* __restrict__ wv, const float* __restrict__ wo,
    u16* __restrict__ wqT, u16* __restrict__ wkT,
    u16* __restrict__ wvT, u16* __restrict__ woT) {
  __shared__ float tile[32][33];
  int bid = blockIdx.x;
  if (bid < 8192) {
    int i = (bid * 256 + threadIdx.x) * 4;
    float4 v = *reinterpret_cast<const float4*>(x + i);
    u16x4 o;
    o[0] = f2bf(v.x); o[1] = f2bf(v.y); o[2] = f2bf(v.z); o[3] = f2bf(v.w);
    *reinterpret_cast<u16x4*>(xb + i) = o;
    return;
  }
  bid -= 8192;
  constexpr int K = 2048;
  const float* w_;
  u16* wt;
  int N;
  switch (bid >> 12) {
    case 0: w_ = wq; wt = wqT; N = 2048; break;
    case 1: w_ = wo; wt = woT; N = 2048; break;
    case 2: w_ = wk; wt = wkT; N = 512; break;
    default: w_ = wv; wt = wvT; N = 512; break;
  }
  int rem = bid & 4095;
  int bx = (rem & 63) * 32;  // n
  if (bx >= N) return;
  int by = (rem >> 6) * 32;  // k
  int tx = threadIdx.x & 31, ty = threadIdx.x >> 5;
#pragma unroll
  for (int i = 0; i < 32; i += 8)
    tile[ty + i][tx] = w_[(size_t)(by + ty + i) * N + bx + tx];
  __syncthreads();
#pragma unroll
  for (int i = 0; i < 32; i += 8)
    wt[(size_t)(bx + ty + i) * K + by + tx] = f2bf(tile[tx][ty + i]);
}

// ---------------- GEMM 256x256 QKV, BK=64, 8 waves, 4-phase counted-vmcnt ------
// (R9-verified schedule.) MODE 3 split: cols [0,2048)->Q (ld2048, xQSCALE),
// [2048,2560)->K (ld512), [2560,3072)->V written DIRECTLY TRANSPOSED into
// VT[(b*512+col)][t].
template <int MODE>
__global__ __launch_bounds__(512, 2) void gemm256(
    const u16* __restrict__ A, const u16* __restrict__ BT,
    float* __restrict__ Cf, u16* __restrict__ Cb, u16* __restrict__ Cb2,
    u16* __restrict__ Cb3, int M, int N) {
  constexpr int K = 2048, NT = 32;
  __shared__ __align__(16) u16 Ab[2][256 * 64];
  __shared__ __align__(16) u16 Bb[2][256 * 64];
  const int t = threadIdx.x;
  const int lane = t & 63;
  const int w = t >> 6;
  const int wm = w >> 2, wn = w & 3;
  const int l15 = lane & 15, l4 = lane >> 4;

  const int nwg = gridDim.x * gridDim.y;
  const int bid = blockIdx.y * gridDim.x + blockIdx.x;
  const int wg = (bid & 7) * (nwg >> 3) + (bid >> 3);
  const int brow = (wg / gridDim.x) * 256;
  const int bcol = (wg % gridDim.x) * 256;

  const int r0 = t >> 3;
  const int gc = ((t & 7) ^ (r0 & 7)) * 8;
  auto stageA = [&](int q, int h, int kt) {
    const u16* src = A + (size_t)(brow + h * 128 + r0) * K + kt * 64 + gc;
    u16* dst = &Ab[q][(h * 128 + r0) * 64 + (t & 7) * 8];
    gload_lds16(src, dst);
    gload_lds16(src + (size_t)64 * K, dst + 64 * 64);
  };
  auto stageB = [&](int q, int h, int kt) {
    const u16* src = BT + (size_t)(bcol + h * 128 + r0) * K + kt * 64 + gc;
    u16* dst = &Bb[q][(h * 128 + r0) * 64 + (t & 7) * 8];
    gload_lds16(src, dst);
    gload_lds16(src + (size_t)64 * K, dst + 64 * 64);
  };

  f32x4 acc[8][4];
#pragma unroll
  for (int mi = 0; mi < 8; mi++)
#pragma unroll
    for (int n = 0; n < 4; n++)
#pragma unroll
      for (int r = 0; r < 4; r++) acc[mi][n][r] = 0.f;

  stageA(0, 0, 0); stageA(0, 1, 0);
  stageB(0, 0, 0); stageB(0, 1, 0);
  stageA(1, 0, 1); stageA(1, 1, 1);
  asm volatile("s_waitcnt vmcnt(4)" ::: "memory");
  __builtin_amdgcn_sched_barrier(0);
  __builtin_amdgcn_s_barrier();

  for (int kt = 0; kt < NT; ++kt) {
    const int q = kt & 1;
    const u16* Al = Ab[q];
    const u16* Bl = Bb[q];
    bf16x8 af[8][2], bf[4][2];

    // P1
#pragma unroll
    for (int m = 0; m < 4; ++m) {
      int row = wm * 128 + m * 16 + l15;
#pragma unroll
      for (int ks = 0; ks < 2; ++ks)
        af[m][ks] = *reinterpret_cast<const bf16x8*>(
            &Al[row * 64 + (((ks * 4 + l4) ^ (row & 7)) * 8)]);
    }
#pragma unroll
    for (int n = 0; n < 2; ++n) {
      int row = wn * 64 + n * 16 + l15;
#pragma unroll
      for (int ks = 0; ks < 2; ++ks)
        bf[n][ks] = *reinterpret_cast<const bf16x8*>(
            &Bl[row * 64 + (((ks * 4 + l4) ^ (row & 7)) * 8)]);
    }
    if (kt + 1 < NT) stageB(q ^ 1, 0, kt + 1);
    __builtin_amdgcn_s_barrier();
    __builtin_amdgcn_s_setprio(1);
#pragma unroll
    for (int ks = 0; ks < 2; ++ks)
#pragma unroll
      for (int m = 0; m < 4; ++m)
#pragma unroll
        for (int n = 0; n < 2; ++n)
          acc[m][n] = __builtin_amdgcn_mfma_f32_16x16x32_bf16(
              af[m][ks], bf[n][ks], acc[m][n], 0, 0, 0);
    __builtin_amdgcn_s_setprio(0);
    __builtin_amdgcn_s_barrier();

    // P2
#pragma unroll
    for (int m = 4; m < 8; ++m) {
      int row = wm * 128 + m * 16 + l15;
#pragma unroll
      for (int ks = 0; ks < 2; ++ks)
        af[m][ks] = *reinterpret_cast<const bf16x8*>(
            &Al[row * 64 + (((ks * 4 + l4) ^ (row & 7)) * 8)]);
    }
#pragma unroll
    for (int n = 2; n < 4; ++n) {
      int row = wn * 64 + n * 16 + l15;
#pragma unroll
      for (int ks = 0; ks < 2; ++ks)
        bf[n][ks] = *reinterpret_cast<const bf16x8*>(
            &Bl[row * 64 + (((ks * 4 + l4) ^ (row & 7)) * 8)]);
    }
    if (kt + 1 < NT) stageB(q ^ 1, 1, kt + 1);
    __builtin_amdgcn_s_barrier();
    __builtin_amdgcn_s_setprio(1);
#pragma unroll
    for (int ks = 0; ks < 2; ++ks)
#pragma unroll
      for (int m = 0; m < 4; ++m)
#pragma unroll
        for (int n = 2; n < 4; ++n)
          acc[m][n] = __builtin_amdgcn_mfma_f32_16x16x32_bf16(
              af[m][ks], bf[n][ks], acc[m][n], 0, 0, 0);
    __builtin_amdgcn_s_setprio(0);
    __builtin_amdgcn_s_barrier();

    // P3
    if (kt + 2 < NT) stageA(q, 0, kt + 2);
    __builtin_amdgcn_s_barrier();
    __builtin_amdgcn_s_setprio(1);
#pragma unroll
    for (int ks = 0; ks < 2; ++ks)
#pragma unroll
      for (int m = 4; m < 8; ++m)
#pragma unroll
        for (int n = 0; n < 2; ++n)
          acc[m][n] = __builtin_amdgcn_mfma_f32_16x16x32_bf16(
              af[m][ks], bf[n][ks], acc[m][n], 0, 0, 0);
    __builtin_amdgcn_s_setprio(0);
    __builtin_amdgcn_s_barrier();

    // P4
    if (kt + 2 < NT) stageA(q, 1, kt + 2);
    __builtin_amdgcn_s_barrier();
    __builtin_amdgcn_s_setprio(1);
#pragma unroll
    for (int ks = 0; ks < 2; ++ks)
#pragma unroll
      for (int m = 4; m < 8; ++m)
#pragma unroll
        for (int n = 2; n < 4; ++n)
          acc[m][n] = __builtin_amdgcn_mfma_f32_16x16x32_bf16(
              af[m][ks], bf[n][ks], acc[m][n], 0, 0, 0);
    __builtin_amdgcn_s_setprio(0);
    if (kt + 2 < NT) {
      asm volatile("s_waitcnt vmcnt(4)" ::: "memory");
    } else {
      asm volatile("s_waitcnt vmcnt(0)" ::: "memory");
    }
    __builtin_amdgcn_sched_barrier(0);
    __builtin_amdgcn_s_barrier();
  }

  // ---- epilogue ----
#pragma unroll
  for (int mi = 0; mi < 8; ++mi) {
    int grow0 = brow + wm * 128 + mi * 16 + l4 * 4;
#pragma unroll
    for (int n = 0; n < 4; ++n) {
      int gcol = bcol + wn * 64 + n * 16 + l15;
      if (MODE == 1) {
#pragma unroll
        for (int r = 0; r < 4; ++r)
          Cf[(size_t)(grow0 + r) * N + gcol] = acc[mi][n][r];
      } else if (bcol < 2048) {
#pragma unroll
        for (int r = 0; r < 4; ++r)
          Cb[(size_t)(grow0 + r) * 2048 + gcol] = f2bf(acc[mi][n][r] * QSCALE);
      } else if (bcol < 2560) {
#pragma unroll
        for (int r = 0; r < 4; ++r)
          Cb2[(size_t)(grow0 + r) * 512 + (gcol - 2048)] = f2bf(acc[mi][n][r]);
      } else {
        int col = gcol - 2560;
        int bb = grow0 >> 11, tt = grow0 & 2047;
        u64 wv = (u64)packbf2(acc[mi][n][0], acc[mi][n][1]) |
                 ((u64)packbf2(acc[mi][n][2], acc[mi][n][3]) << 32);
        *reinterpret_cast<u64*>(&Cb3[((size_t)(bb * 512 + col)) * 2048 + tt]) = wv;
      }
    }
  }
}

// ---------------- GEMM 256x128 (wo), BK=64, 8 waves, 4-phase counted-vmcnt -----
__global__ __launch_bounds__(512, 2) void gemm256n(
    const u16* __restrict__ A, const u16* __restrict__ BT,
    float* __restrict__ Cf, int M, int N) {
  constexpr int K = 2048, NT = 32;
  __shared__ __align__(16) u16 Ab[2][256 * 64];
  __shared__ __align__(16) u16 Bb[2][128 * 64];
  const int t = threadIdx.x;
  const int lane = t & 63;
  const int w = t >> 6;
  const int wm = w >> 1, wn = w & 1;
  const int l15 = lane & 15, l4 = lane >> 4;

  const int nwg = gridDim.x * gridDim.y;
  const int bid = blockIdx.y * gridDim.x + blockIdx.x;
  const int wg = (bid & 7) * (nwg >> 3) + (bid >> 3);
  const int brow = (wg / gridDim.x) * 256;
  const int bcol = (wg % gridDim.x) * 128;

  const int r0 = t >> 3;
  const int gc = ((t & 7) ^ (r0 & 7)) * 8;
  auto stageA = [&](int q, int h, int kt) {
    const u16* src = A + (size_t)(brow + h * 128 + r0) * K + kt * 64 + gc;
    u16* dst = &Ab[q][(h * 128 + r0) * 64 + (t & 7) * 8];
    gload_lds16(src, dst);
    gload_lds16(src + (size_t)64 * K, dst + 64 * 64);
  };
  auto stageB = [&](int q, int h, int kt) {
    const u16* src = BT + (size_t)(bcol + h * 64 + r0) * K + kt * 64 + gc;
    u16* dst = &Bb[q][(h * 64 + r0) * 64 + (t & 7) * 8];
    gload_lds16(src, dst);
  };

  f32x4 acc[4][4];
#pragma unroll
  for (int m = 0; m < 4; m++)
#pragma unroll
    for (int n = 0; n < 4; n++)
#pragma unroll
      for (int r = 0; r < 4; r++) acc[m][n][r] = 0.f;

  stageA(0, 0, 0); stageA(0, 1, 0);
  stageB(0, 0, 0); stageB(0, 1, 0);
  stageA(1, 0, 1); stageA(1, 1, 1);
  asm volatile("s_waitcnt vmcnt(4)" ::: "memory");
  __builtin_amdgcn_sched_barrier(0);
  __builtin_amdgcn_s_barrier();

  for (int kt = 0; kt < NT; ++kt) {
    const int q = kt & 1;
    const u16* Al = Ab[q];
    const u16* Bl = Bb[q];
    bf16x8 af[4][2], bf[4][2];

    // P1
#pragma unroll
    for (int m = 0; m < 2; ++m) {
      int row = wm * 64 + m * 16 + l15;
#pragma unroll
      for (int ks = 0; ks < 2; ++ks)
        af[m][ks] = *reinterpret_cast<const bf16x8*>(
            &Al[row * 64 + (((ks * 4 + l4) ^ (row & 7)) * 8)]);
    }
#pragma unroll
    for (int n = 0; n < 2; ++n) {
      int row = wn * 64 + n * 16 + l15;
#pragma unroll
      for (int ks = 0; ks < 2; ++ks)
        bf[n][ks] = *reinterpret_cast<const bf16x8*>(
            &Bl[row * 64 + (((ks * 4 + l4) ^ (row & 7)) * 8)]);
    }
    if (kt + 1 < NT) stageB(q ^ 1, 0, kt + 1);
    __builtin_amdgcn_s_barrier();
    __builtin_amdgcn_s_setprio(1);
#pragma unroll
    for (int ks = 0; ks < 2; ++ks)
#pragma unroll
      for (int m = 0; m < 2; ++m)
#pragma unroll
        for (int n = 0; n < 2; ++n)
          acc[m][n] = __builtin_amdgcn_mfma_f32_16x16x32_bf16(
              af[m][ks], bf[n][ks], acc[m][n], 0, 0, 0);
    __builtin_amdgcn_s_setprio(0);
    __builtin_amdgcn_s_barrier();

    // P2
#pragma unroll
    for (int m = 2; m < 4; ++m) {
      int row = wm * 64 + m * 16 + l15;
#pragma unroll
      for (int ks = 0; ks < 2; ++ks)
        af[m][ks] = *reinterpret_cast<const bf16x8*>(
            &Al[row * 64 + (((ks * 4 + l4) ^ (row & 7)) * 8)]);
    }
#pragma unroll
    for (int n = 2; n < 4; ++n) {
      int row = wn * 64 + n * 16 + l15;
#pragma unroll
      for (int ks = 0; ks < 2; ++ks)
        bf[n][ks] = *reinterpret_cast<const bf16x8*>(
            &Bl[row * 64 + (((ks * 4 + l4) ^ (row & 7)) * 8)]);
    }
    if (kt + 1 < NT) stageB(q ^ 1, 1, kt + 1);
    __builtin_amdgcn_s_barrier();
    __builtin_amdgcn_s_setprio(1);
#pragma unroll
    for (int ks = 0; ks < 2; ++ks)
#pragma unroll
      for (int m = 0; m < 2; ++m)
#pragma unroll
        for (int n = 2; n < 4; ++n)
          acc[m][n] = __builtin_amdgcn_mfma_f32_16x16x32_bf16(
              af[m][ks], bf[n][ks], acc[m][n], 0, 0, 0);
    __builtin_amdgcn_s_setprio(0);
    __builtin_amdgcn_s_barrier();

    // P3
    if (kt + 2 < NT) stageA(q, 0, kt + 2);
    __builtin_amdgcn_s_barrier();
    __builtin_amdgcn_s_setprio(1);
#pragma unroll
    for (int ks = 0; ks < 2; ++ks)
#pragma unroll
      for (int m = 2; m < 4; ++m)
#pragma unroll
        for (int n = 0; n < 2; ++n)
          acc[m][n] = __builtin_amdgcn_mfma_f32_16x16x32_bf16(
              af[m][ks], bf[n][ks], acc[m][n], 0, 0, 0);
    __builtin_amdgcn_s_setprio(0);
    __builtin_amdgcn_s_barrier();

    // P4
    if (kt + 2 < NT) stageA(q, 1, kt + 2);
    __builtin_amdgcn_s_barrier();
    __builtin_amdgcn_s_setprio(1);
#pragma unroll
    for (int ks = 0; ks < 2; ++ks)
#pragma unroll
      for (int m = 2; m < 4; ++m)
#pragma unroll
        for (int n = 2; n < 4; ++n)
          acc[m][n] = __builtin_amdgcn_mfma_f32_16x16x32_bf16(
              af[m][ks], bf[n][ks], acc[m][n], 0, 0, 0);
    __builtin_amdgcn_s_setprio(0);
    if (kt + 2 < NT) {
      asm volatile("s_waitcnt vmcnt(4)" ::: "memory");
    } else {
      asm volatile("s_waitcnt vmcnt(0)" ::: "memory");
    }
    __builtin_amdgcn_sched_barrier(0);
    __builtin_amdgcn_s_barrier();
  }

#pragma unroll
  for (int m = 0; m < 4; ++m) {
    int grow0 = brow + wm * 64 + m * 16 + l4 * 4;
#pragma unroll
    for (int n = 0; n < 4; ++n) {
      int gcol = bcol + wn * 64 + n * 16 + l15;
#pragma unroll
      for (int r = 0; r < 4; ++r)
        Cf[(size_t)(grow0 + r) * N + gcol] = acc[m][n][r];
    }
  }
}

// ---------------- flash attention v8 (causal, GQA, swapped QK^T, XCD-local) ----
// 1D grid of 1024; decode puts ALL 64 blocks sharing one (b,kvh) K/V stream on
// ONE XCD (bx%8 == kvh): K/V 1MB + Q-slice 2MB fit that XCD's 4MB L2, so the
// per-step staging prefetch hits L2 (~200cy) instead of HBM (~900cy).
// QBLK=64, 4 waves of 16 q-rows, LDS 40KB -> 4 blocks/CU.
// Block jj: q-tile (31-jj) then jj -> 33 steps uniformly.
__global__ __launch_bounds__(256, 4) void attn_kernel(
    const u16* __restrict__ Qb, const u16* __restrict__ Kb,
    const u16* __restrict__ VT, u16* __restrict__ Ob) {
  const int bx = blockIdx.x;
  const int kvh = bx & 7;        // XCD slot == kvh
  const int u = bx >> 3;
  const int jj = u & 15;         // pairing index
  const int v = u >> 4;          // 0..7
  const int h = kvh * 4 + (v & 3);
  const int b = v >> 2;
  const int t = threadIdx.x;
  const int lane = t & 63;
  const int w = t >> 6;
  const int q15 = lane & 15, g = lane >> 4;

  __shared__ __align__(16) u16 Ks[2][64 * 64];
  __shared__ __align__(16) u16 Vs[2][64 * 64];  // V^T tile: [d][kv]
  __shared__ __align__(16) u32 Pu[4][16 * 32];  // per-wave P / epilogue buffer

  const size_t Krow0 = (size_t)b * 2048;
  const size_t Vrow0 = ((size_t)b * 8 + kvh) * 64;

  u16* const dk0 = &Ks[0][t * 8];
  u16* const dk1 = &Ks[1][t * 8];
  u16* const dv0 = &Vs[0][t * 8];
  u16* const dv1 = &Vs[1][t * 8];
  const int row0 = t >> 3;  // 0..31
  const int gcs = ((t & 7) ^ (row0 & 7)) * 8;
  const u16* const pk0 = Kb + (Krow0 + row0) * 512 + kvh * 64 + gcs;
  const u16* const pv0 = VT + (Vrow0 + row0) * 2048 + gcs;
  const u16* kp = pk0;
  const u16* vp = pv0;

  auto stage = [&](int buf, const u16* kpp, const u16* vpp) {
    u16* dk = buf ? dk1 : dk0;
    u16* dv = buf ? dv1 : dv0;
    gload_lds16(kpp, dk);
    gload_lds16(kpp + 32 * 512, dk + 2048);
    gload_lds16(vpp, dv);
    gload_lds16(vpp + 32 * 2048, dv + 2048);
  };

  const int swzB = (q15 & 7) << 3;
  const int swzP = (q15 & 7) << 2;
  u32* const pw = &Pu[w][0];
  const int nA = 32 - jj;
  const int nsteps = 33;

  stage(0, kp, vp);
  __syncthreads();
  int cur = 0;
  int ss = 0;

#pragma unroll
  for (int ph = 0; ph < 2; ++ph) {
    const int qt = ph ? jj : 31 - jj;
    const int nkv = qt + 1;
    const int wq0 = qt * 64 + w * 16;

    bf16x8 qf[2];
    {
      const u16* q0 = &Qb[((size_t)b * 2048 + wq0 + q15) * 2048 + h * 64 + g * 8];
      qf[0] = *reinterpret_cast<const bf16x8*>(q0);
      qf[1] = *reinterpret_cast<const bf16x8*>(q0 + 32);
    }

    f32x4 oo[4];
#pragma unroll
    for (int c = 0; c < 4; c++)
#pragma unroll
      for (int r = 0; r < 4; r++) oo[c][r] = 0.f;
    float mr = -1e30f, lr = 0.f;

    for (int kv = 0; kv < nkv; ++kv, ++ss) {
      const int kvbase = kv << 6;
      if (ss + 1 < nsteps) {
        if (ss + 1 == nA) {
          kp = pk0;
          vp = pv0;
        } else {
          kp += 64 * 512;
          vp += 64;
        }
        stage(cur ^ 1, kp, vp);
      }

      f32x4 s[4];
#pragma unroll
      for (int c = 0; c < 4; c++)
#pragma unroll
        for (int r = 0; r < 4; r++) s[c][r] = 0.f;
      __builtin_amdgcn_s_setprio(1);
#pragma unroll
      for (int ks = 0; ks < 2; ++ks) {
        const int kcol = (ks * 32 + g * 8) ^ swzB;
#pragma unroll
        for (int c = 0; c < 4; c++) {
          bf16x8 kb = *reinterpret_cast<const bf16x8*>(
              &Ks[cur][(c * 16 + q15) * 64 + kcol]);
          s[c] = __builtin_amdgcn_mfma_f32_16x16x32_bf16(kb, qf[ks], s[c], 0, 0, 0);
        }
      }
      __builtin_amdgcn_s_setprio(0);

      if (kv == qt) {
        const int qg = wq0 + q15;
#pragma unroll
        for (int c = 0; c < 4; c++)
#pragma unroll
          for (int r = 0; r < 4; r++)
            if (kvbase + c * 16 + g * 4 + r > qg) s[c][r] = -1e30f;
      }

      float mx0 = fmaxf(fmaxf(s[0][0], s[0][1]), fmaxf(s[0][2], s[0][3]));
      float mx1 = fmaxf(fmaxf(s[1][0], s[1][1]), fmaxf(s[1][2], s[1][3]));
      float mx2 = fmaxf(fmaxf(s[2][0], s[2][1]), fmaxf(s[2][2], s[2][3]));
      float mx3 = fmaxf(fmaxf(s[3][0], s[3][1]), fmaxf(s[3][2], s[3][3]));
      float mx = fmaxf(fmaxf(mx0, mx1), fmaxf(mx2, mx3));
      mx = fmaxf(mx, __shfl_xor(mx, 16));
      mx = fmaxf(mx, __shfl_xor(mx, 32));
      if (!__all(mx <= mr + 8.f)) {
        float mnew = fmaxf(mr, mx);
        float alpha = fexp2(mr - mnew);
        lr *= alpha;
#pragma unroll
        for (int c = 0; c < 4; c++)
#pragma unroll
          for (int r = 0; r < 4; r++) oo[c][r] *= alpha;
        mr = mnew;
      }
      float p[4][4];
      float rs = 0.f;
#pragma unroll
      for (int c = 0; c < 4; c++) {
        float t0 = fexp2(s[c][0] - mr);
        float t1 = fexp2(s[c][1] - mr);
        float t2 = fexp2(s[c][2] - mr);
        float t3 = fexp2(s[c][3] - mr);
        p[c][0] = t0; p[c][1] = t1; p[c][2] = t2; p[c][3] = t3;
        rs += (t0 + t1) + (t2 + t3);
      }
      rs += __shfl_xor(rs, 16);
      rs += __shfl_xor(rs, 32);
      lr += rs;
#pragma unroll
      for (int c = 0; c < 4; c++) {
        u64 wv = (u64)packbf2(p[c][0], p[c][1]) |
                 ((u64)packbf2(p[c][2], p[c][3]) << 32);
        *reinterpret_cast<u64*>(&pw[q15 * 32 + ((c * 8 + g * 2) ^ swzP)]) = wv;
      }
      bf16x8 pb[2];
#pragma unroll
      for (int ks = 0; ks < 2; ++ks)
        pb[ks] = *reinterpret_cast<const bf16x8*>(
            &pw[q15 * 32 + ((ks * 16 + g * 4) ^ swzP)]);

      __builtin_amdgcn_s_setprio(1);
#pragma unroll
      for (int ks = 0; ks < 2; ++ks) {
        const int vcol = (ks * 32 + g * 8) ^ swzB;
#pragma unroll
        for (int c2 = 0; c2 < 4; c2++) {
          bf16x8 vb = *reinterpret_cast<const bf16x8*>(
              &Vs[cur][(c2 * 16 + q15) * 64 + vcol]);
          oo[c2] = __builtin_amdgcn_mfma_f32_16x16x32_bf16(vb, pb[ks], oo[c2], 0, 0, 0);
        }
      }
      __builtin_amdgcn_s_setprio(0);

      __syncthreads();
      cur ^= 1;
    }

    const int qq = lane >> 2, cl = lane & 3;
    const int swq = (qq & 7) << 2;
    {
      float rcp = 1.0f / lr;
#pragma unroll
      for (int c2 = 0; c2 < 4; c2++) {
        u64 wv = (u64)packbf2(oo[c2][0] * rcp, oo[c2][1] * rcp) |
                 ((u64)packbf2(oo[c2][2] * rcp, oo[c2][3] * rcp) << 32);
        *reinterpret_cast<u64*>(&pw[q15 * 32 + ((c2 * 8 + g * 2) ^ swzP)]) = wv;
      }
      uint4 d0 = *reinterpret_cast<const uint4*>(&pw[qq * 32 + ((cl * 4) ^ swq)]);
      uint4 d1 = *reinterpret_cast<const uint4*>(&pw[qq * 32 + ((cl * 4 + 16) ^ swq)]);
      u32* og = (u32*)Ob + ((size_t)b * 2048 + wq0 + qq) * 1024 + h * 32;
      *reinterpret_cast<uint4*>(&og[cl * 4]) = d0;
      *reinterpret_cast<uint4*>(&og[cl * 4 + 16]) = d1;
    }
  }
}

// ---------------- launcher ----------------
extern "C" void kernel_launch(void* const* d_in, const int* in_sizes, int n_in,
                              void* d_out, int out_size, void* d_ws, size_t ws_size,
                              hipStream_t stream) {
  const float* x = (const float*)d_in[0];
  const float* wq = (const float*)d_in[1];
  const float* wk = (const float*)d_in[2];
  const float* wv = (const float*)d_in[3];
  const float* wo = (const float*)d_in[4];
  float* out = (float*)d_out;

  char* p = (char*)d_ws;
  u16* xb = (u16*)p;   p += (size_t)4096 * 2048 * 2;
  u16* wqT = (u16*)p;  p += (size_t)2048 * 2048 * 2;  // wqT|wkT|wvT contiguous
  u16* wkT = (u16*)p;  p += (size_t)512 * 2048 * 2;
  u16* wvT = (u16*)p;  p += (size_t)512 * 2048 * 2;
  u16* woT = (u16*)p;  p += (size_t)2048 * 2048 * 2;
  u16* Qb = (u16*)p;   p += (size_t)4096 * 2048 * 2;
  u16* Kb = (u16*)p;   p += (size_t)4096 * 512 * 2;
  u16* VTb = (u16*)p;  p += (size_t)2 * 512 * 2048 * 2;
  u16* attn = xb;  // reuse: x_bf16 dead after projections

  prep_kernel<<<8192 + 16384, 256, 0, stream>>>(
      x, xb, wq, wk, wv, wo, wqT, wkT, wvT, woT);

  // fused Q|K|V projection — V written directly transposed
  gemm256<3><<<dim3(3072 / 256, 4096 / 256), 512, 0, stream>>>(
      xb, wqT, nullptr, Qb, Kb, VTb, 4096, 3072);

  attn_kernel<<<1024, 256, 0, stream>>>(Qb, Kb, VTb, attn);

  // wo projection — 256x128-tile 4-phase pipeline, 256 blocks = full fill
  gemm256n<<<dim3(2048 / 128, 4096 / 256), 512, 0, stream>>>(
      attn, woT, out, 4096, 2048);
}